// Round 11
// baseline (2403.930 us; speedup 1.0000x reference)
//
#include <hip/hip_runtime.h>
#include <hip/hip_fp16.h>

typedef _Float16 f16;
typedef _Float16 f16x8 __attribute__((ext_vector_type(8)));
typedef float f32x4 __attribute__((ext_vector_type(4)));

#define N_NODES 50000
#define N_EDGES 600000
#define G_GRAPHS 128
#define H 128
#define NP 50176              // 196*256, padded node count for scan
#define NT_E 18750            // 600000/32 exact
#define NB_E 1024             // edge-kernel grid (8*128 for XCD remap)
#define NT_N 1563             // ceil(50000/32)

// ---------------------------------------------------------------------------
// f0 = relu(node_f @ W_in + b_in)  -> fh (f16)
// ---------------------------------------------------------------------------
__global__ void k_f0(const float* __restrict__ node_f, const float* __restrict__ W_in,
                     const float* __restrict__ b_in, f16* __restrict__ fh)
{
    __shared__ float sW[32 * 128];
    __shared__ float sx[8][32];
    const int tid = threadIdx.x;     // 128 threads
    const int base = blockIdx.x * 8;
    for (int i = tid; i < 32 * 128; i += 128) sW[i] = W_in[i];
    for (int i = tid; i < 8 * 32; i += 128) {
        int u = i >> 5, k = i & 31;
        int n = base + u;
        sx[u][k] = (n < N_NODES) ? node_f[(size_t)n * 32 + k] : 0.0f;
    }
    __syncthreads();
    const float bj = b_in[tid];
    #pragma unroll
    for (int u = 0; u < 8; ++u) {
        int n = base + u;
        if (n >= N_NODES) break;
        float acc = bj;
        #pragma unroll
        for (int k = 0; k < 32; ++k) acc = fmaf(sx[u][k], sW[k * 128 + tid], acc);
        fh[(size_t)n * H + tid] = (f16)fmaxf(acc, 0.0f);
    }
}

// ---------------------------------------------------------------------------
// CSR build: histogram, scan, idx scatter, sequential gather (dst-sorted perm)
// ---------------------------------------------------------------------------
__global__ void k_hist(const int* __restrict__ dst, int* __restrict__ cnt)
{
    int e = blockIdx.x * 256 + threadIdx.x;
    if (e < N_EDGES) atomicAdd(&cnt[dst[e]], 1);
}

__global__ void k_scanA(const int* __restrict__ cnt, int* __restrict__ rowptr,
                        int* __restrict__ bsum)
{
    __shared__ int s[256];
    const int t = threadIdx.x;
    const int i = blockIdx.x * 256 + t;
    int v = cnt[i];
    s[t] = v;
    __syncthreads();
    #pragma unroll
    for (int off = 1; off < 256; off <<= 1) {
        int x = (t >= off) ? s[t - off] : 0;
        __syncthreads();
        s[t] += x;
        __syncthreads();
    }
    rowptr[i] = s[t] - v;
    if (t == 255) bsum[blockIdx.x] = s[255];
}

__global__ void k_scanB(const int* __restrict__ bsum, int* __restrict__ boff)
{
    __shared__ int s[256];
    const int t = threadIdx.x;
    int v = (t < 196) ? bsum[t] : 0;
    s[t] = v;
    __syncthreads();
    #pragma unroll
    for (int off = 1; off < 256; off <<= 1) {
        int x = (t >= off) ? s[t - off] : 0;
        __syncthreads();
        s[t] += x;
        __syncthreads();
    }
    boff[t] = s[t] - v;
}

__global__ void k_scanC(int* __restrict__ rowptr, const int* __restrict__ boff)
{
    int i = blockIdx.x * 256 + threadIdx.x;
    rowptr[i] += boff[blockIdx.x];
}

__global__ void k_scatter_idx(const int* __restrict__ dst, const int* __restrict__ rowptr,
                              int* __restrict__ fill, int* __restrict__ perm_eidx)
{
    int e = blockIdx.x * 256 + threadIdx.x;
    if (e >= N_EDGES) return;
    int d = dst[e];
    int p = rowptr[d] + atomicAdd(&fill[d], 1);
    perm_eidx[p] = e;
}

__global__ void k_gather(const int* __restrict__ perm_eidx, const float* __restrict__ edge_w,
                         const int* __restrict__ src, const int* __restrict__ dst,
                         const float* __restrict__ node_x,
                         int* __restrict__ perm_src, int* __restrict__ perm_dst,
                         float* __restrict__ perm_sq, f16* __restrict__ perm_ewh)
{
    int pp = blockIdx.x * 256 + threadIdx.x;
    if (pp >= N_EDGES) return;
    int e = perm_eidx[pp];
    int s = src[e], d = dst[e];
    float dx = node_x[s * 3 + 0] - node_x[d * 3 + 0];
    float dy = node_x[s * 3 + 1] - node_x[d * 3 + 1];
    float dz = node_x[s * 3 + 2] - node_x[d * 3 + 2];
    perm_src[pp] = s;
    perm_dst[pp] = d;
    perm_sq[pp] = dx * dx + dy * dy + dz * dz;
    const float4* pw = (const float4*)(edge_w + (size_t)e * 16);
    float4 w0 = pw[0], w1 = pw[1], w2 = pw[2], w3 = pw[3];
    f16x8 v0, v1;
    v0[0] = (f16)w0.x; v0[1] = (f16)w0.y; v0[2] = (f16)w0.z; v0[3] = (f16)w0.w;
    v0[4] = (f16)w1.x; v0[5] = (f16)w1.y; v0[6] = (f16)w1.z; v0[7] = (f16)w1.w;
    v1[0] = (f16)w2.x; v1[1] = (f16)w2.y; v1[2] = (f16)w2.z; v1[3] = (f16)w2.w;
    v1[4] = (f16)w3.x; v1[5] = (f16)w3.y; v1[6] = (f16)w3.z; v1[7] = (f16)w3.w;
    f16x8* q = (f16x8*)(perm_ewh + (size_t)pp * 16);
    q[0] = v0; q[1] = v1;
}

// ---------------------------------------------------------------------------
// Per-layer node projections: Gs = fh @ W1[0:128], Gd = fh @ W1[128:256]
// (no bias — b1 is added in the edge kernel's C-init)
// ---------------------------------------------------------------------------
__global__ __launch_bounds__(256, 3) void k_proj(
    const f16* __restrict__ fh, const float* __restrict__ W1,
    f16* __restrict__ Gs, f16* __restrict__ Gd)
{
    const int tid = threadIdx.x;
    const int wave = tid >> 6;       // 0..3
    const int lane = tid & 63;
    const int l16 = lane & 15;
    const int lq = lane >> 4;
    const int colbase = wave * 32;

    f16x8 wsa[4][2], wsb[4][2];
    #pragma unroll
    for (int nt = 0; nt < 2; ++nt) {
        const int col = colbase + nt * 16 + l16;
        #pragma unroll
        for (int k = 0; k < 4; ++k) {
            f16x8 va, vb;
            #pragma unroll
            for (int j = 0; j < 8; ++j) {
                va[j] = (f16)W1[(size_t)(k * 32 + lq * 8 + j) * H + col];
                vb[j] = (f16)W1[(size_t)(128 + k * 32 + lq * 8 + j) * H + col];
            }
            wsa[k][nt] = va;
            wsb[k][nt] = vb;
        }
    }

    __shared__ alignas(16) f16 U[32][136];
    const int row = tid >> 3, ch = tid & 7;

    int tile = blockIdx.x;
    f16x8 rf0, rf1;
    if (tile < NT_N) {
        int n = min(tile * 32 + row, N_NODES - 1);
        const f16x8* pf = (const f16x8*)(fh + (size_t)n * H) + ch * 2;
        rf0 = pf[0]; rf1 = pf[1];
    }
    for (; tile < NT_N; tile += gridDim.x) {
        const int n0 = tile * 32;
        {
            int4* q0 = (int4*)(&U[row][ch * 16]);
            q0[0] = *(const int4*)&rf0;
            q0[1] = *(const int4*)&rf1;
        }
        {
            int nt_ = tile + gridDim.x;
            if (nt_ < NT_N) {
                int n = min(nt_ * 32 + row, N_NODES - 1);
                const f16x8* pf = (const f16x8*)(fh + (size_t)n * H) + ch * 2;
                rf0 = pf[0]; rf1 = pf[1];
            }
        }
        __syncthreads();   // B1

        f32x4 accs[2][2], accd[2][2];
        #pragma unroll
        for (int m = 0; m < 2; ++m)
            #pragma unroll
            for (int nt = 0; nt < 2; ++nt) {
                f32x4 z = {0.0f, 0.0f, 0.0f, 0.0f};
                accs[m][nt] = z; accd[m][nt] = z;
            }
        #pragma unroll
        for (int k = 0; k < 4; ++k) {
            #pragma unroll
            for (int m = 0; m < 2; ++m) {
                f16x8 a = *(const f16x8*)&U[m * 16 + l16][k * 32 + lq * 8];
                #pragma unroll
                for (int nt = 0; nt < 2; ++nt) {
                    accs[m][nt] = __builtin_amdgcn_mfma_f32_16x16x32_f16(a, wsa[k][nt], accs[m][nt], 0, 0, 0);
                    accd[m][nt] = __builtin_amdgcn_mfma_f32_16x16x32_f16(a, wsb[k][nt], accd[m][nt], 0, 0, 0);
                }
            }
        }
        #pragma unroll
        for (int m = 0; m < 2; ++m)
            #pragma unroll
            for (int nt = 0; nt < 2; ++nt)
                #pragma unroll
                for (int r = 0; r < 4; ++r) {
                    int rr = m * 16 + lq * 4 + r;
                    int n = n0 + rr;
                    if (n < N_NODES) {
                        int col = colbase + nt * 16 + l16;
                        Gs[(size_t)n * H + col] = (f16)accs[m][nt][r];
                        Gd[(size_t)n * H + col] = (f16)accd[m][nt][r];
                    }
                }
        __syncthreads();   // B2 (U reused next iteration)
    }
}

// ---------------------------------------------------------------------------
// Edge-parallel message kernel, dst-sorted 32-edge tiles, ONE barrier/tile,
// with per-node projections as C-init:
//   h1 = relu( Gs[src] + Gd[dst] + w@W1c + sq*w1last + b1 ),  w = relu(ew@We+be)
// Section t: C-init from Gt[pa] + dc/sq -> issue Gs/Gd/ewh loads(t+1) +
//   meta(t+2) -> mm2(t-1)+atomics(t-1) -> mm1-w(t)->h1B[pa] ->
//   weMFMA(t+1)->Atile[pa^1] -> Gsum(t+1)->Gt[pa^1] -> meta->LDS -> barrier.
// LDS 53 KB -> 3 blocks/CU; fragments dieted to fit 85 VGPR (512,6).
// Hazards: every LDS buffer's write->read crosses exactly one barrier
// (Atile/Gt: written late t, read t+1; h1B: written t, read t+1; meta slots
// distinct mod 3). dcp is a wave-private register carry.
// ---------------------------------------------------------------------------
__global__ __launch_bounds__(512, 6) void k_edge2(
    const f16* __restrict__ Gs, const f16* __restrict__ Gd,
    const int* __restrict__ perm_src, const int* __restrict__ perm_dst,
    const float* __restrict__ perm_sq, const f16* __restrict__ perm_ewh,
    const float* __restrict__ W_e, const float* __restrict__ b_e,
    const float* __restrict__ W1, const float* __restrict__ b1,
    const float* __restrict__ W2, const float* __restrict__ b2,
    f16* __restrict__ msum)
{
    const int tid = threadIdx.x;
    const int wave = tid >> 6;
    const int lane = tid & 63;
    const int l16 = lane & 15;
    const int lq  = lane >> 4;
    const int col = wave * 16 + l16;

    f16x8 wef, w1f[4], w2f[4];
    #pragma unroll
    for (int j = 0; j < 8; ++j) {
        int k = lq * 8 + j;
        wef[j] = (k < 16) ? (f16)W_e[(size_t)k * H + col] : (f16)0.0f;
    }
    #pragma unroll
    for (int k = 0; k < 4; ++k)
        #pragma unroll
        for (int j = 0; j < 8; ++j) {
            w1f[k][j] = (f16)W1[(size_t)(256 + k * 32 + lq * 8 + j) * H + col];
            w2f[k][j] = (f16)W2[(size_t)(k * 32 + lq * 8 + j) * H + col];
        }
    const float w1last = W1[(size_t)384 * H + col];
    const float b1v = b1[col], b2v = b2[col], bev = b_e[col];

    __shared__ alignas(16) f16 Atile[2][32][136];   // w cols only, 17.4 KB
    __shared__ alignas(16) f16 h1B[2][32][136];     // 17.4 KB
    __shared__ alignas(16) f16 Gt[2][32][136];      // Gs[src]+Gd[dst], 17.4 KB
    __shared__ int   s_src[3][32];
    __shared__ int   s_dst[3][32];
    __shared__ float s_sq[3][32];

    const int b = ((blockIdx.x & 7) << 7) | (blockIdx.x >> 3);
    const int t0 = (int)((long)b * NT_E / NB_E);
    const int t1 = (int)((long)(b + 1) * NT_E / NB_E);

    const int srow = tid >> 4, sch = tid & 15;
    const int sj = ((srow >> 2) & 3) * 8 + ((srow >> 4) << 2) + (srow & 3); // eperm

    // ---- prologue ----
    if (tid < 32) {
        int e0 = t0 * 32 + tid;
        s_src[t0 % 3][tid] = perm_src[e0];
        s_dst[t0 % 3][tid] = perm_dst[e0];
        s_sq [t0 % 3][tid] = perm_sq[e0];
        int e1 = min((t0 + 1) * 32 + tid, N_EDGES - 1);
        s_src[(t0 + 1) % 3][tid] = perm_src[e1];
        s_dst[(t0 + 1) % 3][tid] = perm_dst[e1];
        s_sq [(t0 + 1) % 3][tid] = perm_sq[e1];
    }
    __syncthreads();
    {
        const int pa = t0 & 1;
        int sv = s_src[t0 % 3][sj], dv = s_dst[t0 % 3][sj];
        union { int4 i; f16x8 h; } ua, ub, uo;
        ua.i = ((const int4*)(Gs + (size_t)sv * H))[sch];
        ub.i = ((const int4*)(Gd + (size_t)dv * H))[sch];
        #pragma unroll
        for (int j = 0; j < 8; ++j) uo.h[j] = (f16)((float)ua.h[j] + (float)ub.h[j]);
        ((int4*)&Gt[pa][srow][0])[sch] = uo.i;
        #pragma unroll
        for (int m = 0; m < 2; ++m) {
            f16x8 aa;
            if (lq < 2) {
                int j = (l16 >> 2) * 8 + m * 4 + (l16 & 3);
                aa = *(const f16x8*)(perm_ewh + (size_t)(t0 * 32 + j) * 16 + lq * 8);
            } else {
                #pragma unroll
                for (int jj = 0; jj < 8; ++jj) aa[jj] = (f16)0.0f;
            }
            f32x4 c = {bev, bev, bev, bev};
            c = __builtin_amdgcn_mfma_f32_16x16x32_f16(aa, wef, c, 0, 0, 0);
            #pragma unroll
            for (int r = 0; r < 4; ++r)
                Atile[pa][m * 16 + lq * 4 + r][col] = (f16)fmaxf(c[r], 0.0f);
        }
    }
    __syncthreads();

    int dcp[8];
    for (int t = t0; t < t1; ++t) {
        const int pa = t & 1;
        const int m0 = t % 3;
        const int m1 = (t + 1) % 3;
        const int m2 = (t + 2) % 3;

        // 1. dc(t), C-init: b1 + sq*w1last + Gsum
        int dc[8];
        f32x4 acc1[2];
        #pragma unroll
        for (int m = 0; m < 2; ++m)
            #pragma unroll
            for (int r = 0; r < 4; ++r) {
                int j = lq * 8 + m * 4 + r;
                int row = m * 16 + lq * 4 + r;
                dc[m * 4 + r] = s_dst[m0][j];
                acc1[m][r] = fmaf(s_sq[m0][j], w1last, b1v) + (float)Gt[pa][row][col];
            }

        // 2. issue Gs/Gd/ewh loads for tile t+1
        int4 ga_, gb_;
        f16x8 rew[2];
        {
            int sv = s_src[m1][sj], dv = s_dst[m1][sj];
            ga_ = ((const int4*)(Gs + (size_t)sv * H))[sch];
            gb_ = ((const int4*)(Gd + (size_t)dv * H))[sch];
            #pragma unroll
            for (int m = 0; m < 2; ++m) {
                if (lq < 2) {
                    int j = (l16 >> 2) * 8 + m * 4 + (l16 & 3);
                    int e = min((t + 1) * 32 + j, N_EDGES - 1);
                    rew[m] = *(const f16x8*)(perm_ewh + (size_t)e * 16 + lq * 8);
                }
            }
        }
        // 3. meta(t+2)
        int mrs = 0, mrd = 0; float mrq = 0.0f;
        if (tid < 32) {
            int e = min((t + 2) * 32 + tid, N_EDGES - 1);
            mrs = perm_src[e]; mrd = perm_dst[e]; mrq = perm_sq[e];
        }

        // 4+5. mm2(t-1) + atomics
        if (t > t0) {
            f32x4 acc2[2];
            #pragma unroll
            for (int m = 0; m < 2; ++m) {
                f32x4 c = {b2v, b2v, b2v, b2v};
                acc2[m] = c;
            }
            #pragma unroll
            for (int k = 0; k < 4; ++k) {
                #pragma unroll
                for (int m = 0; m < 2; ++m) {
                    f16x8 a = *(const f16x8*)&h1B[pa ^ 1][m * 16 + l16][k * 32 + lq * 8];
                    acc2[m] = __builtin_amdgcn_mfma_f32_16x16x32_f16(a, w2f[k], acc2[m], 0, 0, 0);
                }
            }
            float run = fmaxf(acc2[0][0], 0.0f);
            int cd = dcp[0];
            #pragma unroll
            for (int i = 1; i < 8; ++i) {
                float v = fmaxf(acc2[i >> 2][i & 3], 0.0f);
                int d = dcp[i];
                if (d == cd) {
                    run += v;
                } else {
                    float nb = __shfl_xor(run, 1);
                    if ((l16 & 1) == 0) {
                        union { f16 h[2]; __half2 v2; } u;
                        u.h[0] = (f16)run; u.h[1] = (f16)nb;
                        unsafeAtomicAdd((__half2*)&msum[(size_t)cd * H + col], u.v2);
                    }
                    run = v; cd = d;
                }
            }
            float nb = __shfl_xor(run, 1);
            if ((l16 & 1) == 0) {
                union { f16 h[2]; __half2 v2; } u;
                u.h[0] = (f16)run; u.h[1] = (f16)nb;
                unsafeAtomicAdd((__half2*)&msum[(size_t)cd * H + col], u.v2);
            }
        }

        // 6. mm1-w(t) -> h1B[pa]
        #pragma unroll
        for (int k = 0; k < 4; ++k) {
            #pragma unroll
            for (int m = 0; m < 2; ++m) {
                f16x8 a = *(const f16x8*)&Atile[pa][m * 16 + l16][k * 32 + lq * 8];
                acc1[m] = __builtin_amdgcn_mfma_f32_16x16x32_f16(a, w1f[k], acc1[m], 0, 0, 0);
            }
        }
        #pragma unroll
        for (int m = 0; m < 2; ++m)
            #pragma unroll
            for (int r = 0; r < 4; ++r)
                h1B[pa][m * 16 + lq * 4 + r][col] = (f16)fmaxf(acc1[m][r], 0.0f);

        // 7. we-MFMA(t+1) -> Atile[pa^1]
        #pragma unroll
        for (int m = 0; m < 2; ++m) {
            f16x8 aa;
            if (lq < 2) {
                aa = rew[m];
            } else {
                #pragma unroll
                for (int jj = 0; jj < 8; ++jj) aa[jj] = (f16)0.0f;
            }
            f32x4 c = {bev, bev, bev, bev};
            c = __builtin_amdgcn_mfma_f32_16x16x32_f16(aa, wef, c, 0, 0, 0);
            #pragma unroll
            for (int r = 0; r < 4; ++r)
                Atile[pa ^ 1][m * 16 + lq * 4 + r][col] = (f16)fmaxf(c[r], 0.0f);
        }
        // 8. Gsum(t+1) -> Gt[pa^1]
        {
            union { int4 i; f16x8 h; } ua, ub, uo;
            ua.i = ga_; ub.i = gb_;
            #pragma unroll
            for (int j = 0; j < 8; ++j) uo.h[j] = (f16)((float)ua.h[j] + (float)ub.h[j]);
            ((int4*)&Gt[pa ^ 1][srow][0])[sch] = uo.i;
        }
        // 9. meta(t+2) -> LDS
        if (tid < 32) {
            s_src[m2][tid] = mrs; s_dst[m2][tid] = mrd; s_sq[m2][tid] = mrq;
        }
        // 10. carry dc
        #pragma unroll
        for (int i = 0; i < 8; ++i) dcp[i] = dc[i];
        __syncthreads();
    }

    // ---- epilogue: mm2(t1-1) + atomics ----
    {
        const int ph = (t1 - 1) & 1;
        f32x4 acc2[2];
        #pragma unroll
        for (int m = 0; m < 2; ++m) {
            f32x4 c = {b2v, b2v, b2v, b2v};
            acc2[m] = c;
        }
        #pragma unroll
        for (int k = 0; k < 4; ++k) {
            #pragma unroll
            for (int m = 0; m < 2; ++m) {
                f16x8 a = *(const f16x8*)&h1B[ph][m * 16 + l16][k * 32 + lq * 8];
                acc2[m] = __builtin_amdgcn_mfma_f32_16x16x32_f16(a, w2f[k], acc2[m], 0, 0, 0);
            }
        }
        float run = fmaxf(acc2[0][0], 0.0f);
        int cd = dcp[0];
        #pragma unroll
        for (int i = 1; i < 8; ++i) {
            float v = fmaxf(acc2[i >> 2][i & 3], 0.0f);
            int d = dcp[i];
            if (d == cd) {
                run += v;
            } else {
                float nb = __shfl_xor(run, 1);
                if ((l16 & 1) == 0) {
                    union { f16 h[2]; __half2 v2; } u;
                    u.h[0] = (f16)run; u.h[1] = (f16)nb;
                    unsafeAtomicAdd((__half2*)&msum[(size_t)cd * H + col], u.v2);
                }
                run = v; cd = d;
            }
        }
        float nb = __shfl_xor(run, 1);
        if ((l16 & 1) == 0) {
            union { f16 h[2]; __half2 v2; } u;
            u.h[0] = (f16)run; u.h[1] = (f16)nb;
            unsafeAtomicAdd((__half2*)&msum[(size_t)cd * H + col], u.v2);
        }
    }
}

// ---------------------------------------------------------------------------
// Node update: fh = relu(relu((msum+fh)@U1+b1)@U2+b2), pipelined, 2 barriers.
// ---------------------------------------------------------------------------
__global__ __launch_bounds__(256, 3) void k_update(
    const f16* __restrict__ msum, f16* __restrict__ fh,
    const float* __restrict__ W1, const float* __restrict__ b1,
    const float* __restrict__ W2, const float* __restrict__ b2)
{
    const int tid = threadIdx.x;
    const int wave = tid >> 6;       // 0..3
    const int lane = tid & 63;
    const int l16 = lane & 15;
    const int lq = lane >> 4;
    const int colbase = wave * 32;

    f16x8 w1fr[4][2], w2fr[4][2];
    float b1v[2], b2v[2];
    #pragma unroll
    for (int nt = 0; nt < 2; ++nt) {
        const int col = colbase + nt * 16 + l16;
        #pragma unroll
        for (int k = 0; k < 4; ++k) {
            f16x8 v1, v2;
            #pragma unroll
            for (int j = 0; j < 8; ++j) {
                v1[j] = (f16)W1[(size_t)(k * 32 + lq * 8 + j) * H + col];
                v2[j] = (f16)W2[(size_t)(k * 32 + lq * 8 + j) * H + col];
            }
            w1fr[k][nt] = v1;
            w2fr[k][nt] = v2;
        }
        b1v[nt] = b1[col];
        b2v[nt] = b2[col];
    }

    __shared__ alignas(16) f16 U[32][136];
    __shared__ alignas(16) f16 h1b[32][136];
    const int row = tid >> 3, ch = tid & 7;

    int tile = blockIdx.x;
    f16x8 rm0, rm1, rf0, rf1;
    if (tile < NT_N) {
        int n = min(tile * 32 + row, N_NODES - 1);
        const f16x8* pm = (const f16x8*)(msum + (size_t)n * H) + ch * 2;
        const f16x8* pf = (const f16x8*)(fh + (size_t)n * H) + ch * 2;
        rm0 = pm[0]; rm1 = pm[1]; rf0 = pf[0]; rf1 = pf[1];
    }
    for (; tile < NT_N; tile += gridDim.x) {
        const int n0 = tile * 32;
        {
            f16 tmp[16];
            #pragma unroll
            for (int j = 0; j < 8; ++j) {
                tmp[j]     = (f16)((float)rm0[j] + (float)rf0[j]);
                tmp[8 + j] = (f16)((float)rm1[j] + (float)rf1[j]);
            }
            int4* q0 = (int4*)(&U[row][ch * 16]);
            q0[0] = ((const int4*)tmp)[0];
            q0[1] = ((const int4*)tmp)[1];
        }
        {
            int nt_ = tile + gridDim.x;
            if (nt_ < NT_N) {
                int n = min(nt_ * 32 + row, N_NODES - 1);
                const f16x8* pm = (const f16x8*)(msum + (size_t)n * H) + ch * 2;
                const f16x8* pf = (const f16x8*)(fh + (size_t)n * H) + ch * 2;
                rm0 = pm[0]; rm1 = pm[1]; rf0 = pf[0]; rf1 = pf[1];
            }
        }
        __syncthreads();   // B1

        f32x4 acc[2][2];
        #pragma unroll
        for (int m = 0; m < 2; ++m)
            #pragma unroll
            for (int nt = 0; nt < 2; ++nt) {
                f32x4 c = {b1v[nt], b1v[nt], b1v[nt], b1v[nt]};
                acc[m][nt] = c;
            }
        #pragma unroll
        for (int k = 0; k < 4; ++k) {
            #pragma unroll
            for (int m = 0; m < 2; ++m) {
                f16x8 a = *(const f16x8*)&U[m * 16 + l16][k * 32 + lq * 8];
                #pragma unroll
                for (int nt = 0; nt < 2; ++nt)
                    acc[m][nt] = __builtin_amdgcn_mfma_f32_16x16x32_f16(a, w1fr[k][nt], acc[m][nt], 0, 0, 0);
            }
        }
        #pragma unroll
        for (int m = 0; m < 2; ++m)
            #pragma unroll
            for (int nt = 0; nt < 2; ++nt)
                #pragma unroll
                for (int r = 0; r < 4; ++r)
                    h1b[m * 16 + lq * 4 + r][colbase + nt * 16 + l16] = (f16)fmaxf(acc[m][nt][r], 0.0f);
        __syncthreads();   // B2

        f32x4 acc2[2][2];
        #pragma unroll
        for (int m = 0; m < 2; ++m)
            #pragma unroll
            for (int nt = 0; nt < 2; ++nt) {
                f32x4 c = {b2v[nt], b2v[nt], b2v[nt], b2v[nt]};
                acc2[m][nt] = c;
            }
        #pragma unroll
        for (int k = 0; k < 4; ++k) {
            #pragma unroll
            for (int m = 0; m < 2; ++m) {
                f16x8 a = *(const f16x8*)&h1b[m * 16 + l16][k * 32 + lq * 8];
                #pragma unroll
                for (int nt = 0; nt < 2; ++nt)
                    acc2[m][nt] = __builtin_amdgcn_mfma_f32_16x16x32_f16(a, w2fr[k][nt], acc2[m][nt], 0, 0, 0);
            }
        }
        #pragma unroll
        for (int m = 0; m < 2; ++m)
            #pragma unroll
            for (int nt = 0; nt < 2; ++nt)
                #pragma unroll
                for (int r = 0; r < 4; ++r) {
                    int rr = m * 16 + lq * 4 + r;
                    int n = n0 + rr;
                    if (n < N_NODES)
                        fh[(size_t)n * H + colbase + nt * 16 + l16] = (f16)fmaxf(acc2[m][nt][r], 0.0f);
                }
    }
}

// ---------------------------------------------------------------------------
// Per-graph mean/max readout (graph_ids sorted; f >= 0)
// ---------------------------------------------------------------------------
__global__ void k_readout(const f16* __restrict__ fh, const int* __restrict__ gid,
                          float* __restrict__ gsum, float* __restrict__ gmax,
                          int* __restrict__ gcnt)
{
    __shared__ int s_gid[64];
    const int tid = threadIdx.x;            // 128 threads
    const int base = blockIdx.x * 64;
    if (tid < 64) s_gid[tid] = (base + tid < N_NODES) ? gid[base + tid] : -1;
    __syncthreads();
    if (tid < 64 && base + tid < N_NODES) atomicAdd(&gcnt[s_gid[tid]], 1);

    float lsum = 0.0f, lmax = 0.0f;
    int cur = s_gid[0];
    if (cur >= 0) {
        for (int i = 0; i < 64; ++i) {
            int g = s_gid[i];
            if (g < 0) break;
            if (g != cur) {
                unsafeAtomicAdd(&gsum[(size_t)cur * H + tid], lsum);
                atomicMax((int*)&gmax[(size_t)cur * H + tid], __float_as_int(lmax));
                lsum = 0.0f; lmax = 0.0f; cur = g;
            }
            float v = (float)fh[(size_t)(base + i) * H + tid];
            lsum += v;
            lmax = fmaxf(lmax, v);
        }
        unsafeAtomicAdd(&gsum[(size_t)cur * H + tid], lsum);
        atomicMax((int*)&gmax[(size_t)cur * H + tid], __float_as_int(lmax));
    }
}

__global__ void k_out(const float* __restrict__ gsum, const float* __restrict__ gmax,
                      const int* __restrict__ gcnt, const float* __restrict__ W_out,
                      const float* __restrict__ b_out, float* __restrict__ out)
{
    __shared__ float sm[128], sx[128];
    const int g = blockIdx.x, t = threadIdx.x;
    const float inv = 1.0f / fmaxf((float)gcnt[g], 1.0f);
    sm[t] = gsum[(size_t)g * H + t] * inv;
    sx[t] = gmax[(size_t)g * H + t];
    __syncthreads();
    float acc = b_out[t];
    for (int k = 0; k < H; ++k) {
        acc = fmaf(sm[k], W_out[(size_t)k * 128 + t], acc);
        acc = fmaf(sx[k], W_out[(size_t)(128 + k) * 128 + t], acc);
    }
    out[(size_t)g * 128 + t] = acc;
}

// ---------------------------------------------------------------------------
extern "C" void kernel_launch(void* const* d_in, const int* in_sizes, int n_in,
                              void* d_out, int out_size, void* d_ws, size_t ws_size,
                              hipStream_t stream)
{
    const float* node_f = (const float*)d_in[0];
    const float* node_x = (const float*)d_in[1];
    const float* edge_w = (const float*)d_in[2];
    const int*   src    = (const int*)d_in[3];
    const int*   dst    = (const int*)d_in[4];
    const int*   gid    = (const int*)d_in[5];
    const float* W_in   = (const float*)d_in[6];
    const float* b_in   = (const float*)d_in[7];
    const float* W_e    = (const float*)d_in[8];
    const float* b_e    = (const float*)d_in[9];
    const float* msg_W1 = (const float*)d_in[10];
    const float* msg_b1 = (const float*)d_in[11];
    const float* msg_W2 = (const float*)d_in[12];
    const float* msg_b2 = (const float*)d_in[13];
    const float* upd_W1 = (const float*)d_in[14];
    const float* upd_b1 = (const float*)d_in[15];
    const float* upd_W2 = (const float*)d_in[16];
    const float* upd_b2 = (const float*)d_in[17];
    const float* W_out  = (const float*)d_in[18];
    const float* b_out  = (const float*)d_in[19];
    float* out = (float*)d_out;

    char* ws = (char*)d_ws;
    size_t off = 0;
    f16*   fh       = (f16*)(ws + off);   off += (size_t)N_NODES * H * 2;      // 12.8 MB
    f16*   Gs       = (f16*)(ws + off);   off += (size_t)N_NODES * H * 2;      // 12.8 MB
    f16*   Gd       = (f16*)(ws + off);   off += (size_t)N_NODES * H * 2;      // 12.8 MB
    f16*   perm_ewh = (f16*)(ws + off);   off += (size_t)N_EDGES * 16 * 2;     // 19.2 MB
    int*   perm_src = (int*)(ws + off);   off += (size_t)N_EDGES * 4;          // 2.4 MB
    int*   perm_dst = (int*)(ws + off);   off += (size_t)N_EDGES * 4;          // 2.4 MB
    float* perm_sq  = (float*)(ws + off); off += (size_t)N_EDGES * 4;          // 2.4 MB
    int*   rowptr   = (int*)(ws + off);   off += (size_t)NP * 4;
    int*   cnt      = (int*)(ws + off);   off += (size_t)NP * 4;               // also 'fill'
    int*   bsum     = (int*)(ws + off);   off += 256 * 4;
    int*   boff     = (int*)(ws + off);   off += 256 * 4;
    f16*   msum     = (f16*)(ws + off);   off += (size_t)N_NODES * H * 2;      // 12.8 MB
    float* gsum     = (float*)(ws + off); off += (size_t)G_GRAPHS * H * 4;
    float* gmax     = (float*)(ws + off); off += (size_t)G_GRAPHS * H * 4;
    int*   gcnt     = (int*)(ws + off);   off += (size_t)G_GRAPHS * 4;
    int*   perm_eidx = (int*)msum;        // aliased: eidx only used pre-layers

    k_f0<<<(N_NODES + 7) / 8, 128, 0, stream>>>(node_f, W_in, b_in, fh);

    (void)hipMemsetAsync(cnt, 0, (size_t)NP * 4, stream);
    k_hist<<<(N_EDGES + 255) / 256, 256, 0, stream>>>(dst, cnt);
    k_scanA<<<NP / 256, 256, 0, stream>>>(cnt, rowptr, bsum);
    k_scanB<<<1, 256, 0, stream>>>(bsum, boff);
    k_scanC<<<NP / 256, 256, 0, stream>>>(rowptr, boff);
    (void)hipMemsetAsync(cnt, 0, (size_t)NP * 4, stream);
    k_scatter_idx<<<(N_EDGES + 255) / 256, 256, 0, stream>>>(dst, rowptr, cnt, perm_eidx);
    k_gather<<<(N_EDGES + 255) / 256, 256, 0, stream>>>(perm_eidx, edge_w, src, dst, node_x,
                                                        perm_src, perm_dst, perm_sq, perm_ewh);

    for (int l = 0; l < 4; ++l) {
        (void)hipMemsetAsync(msum, 0, (size_t)N_NODES * H * 2, stream);
        k_proj<<<512, 256, 0, stream>>>(fh, msg_W1 + (size_t)l * 385 * H, Gs, Gd);
        k_edge2<<<NB_E, 512, 0, stream>>>(Gs, Gd, perm_src, perm_dst, perm_sq, perm_ewh,
                                          W_e, b_e,
                                          msg_W1 + (size_t)l * 385 * H, msg_b1 + (size_t)l * H,
                                          msg_W2 + (size_t)l * H * H,  msg_b2 + (size_t)l * H,
                                          msum);
        k_update<<<512, 256, 0, stream>>>(msum, fh,
                                          upd_W1 + (size_t)l * H * H, upd_b1 + (size_t)l * H,
                                          upd_W2 + (size_t)l * H * H, upd_b2 + (size_t)l * H);
    }

    (void)hipMemsetAsync(gsum, 0, (size_t)G_GRAPHS * H * 4, stream);
    (void)hipMemsetAsync(gmax, 0, (size_t)G_GRAPHS * H * 4, stream);
    (void)hipMemsetAsync(gcnt, 0, (size_t)G_GRAPHS * 4, stream);
    k_readout<<<(N_NODES + 63) / 64, 128, 0, stream>>>(fh, gid, gsum, gmax, gcnt);
    k_out<<<G_GRAPHS, 128, 0, stream>>>(gsum, gmax, gcnt, W_out, b_out, out);
}

// Round 12
// 1433.589 us; speedup vs baseline: 1.6769x; 1.6769x over previous
//
#include <hip/hip_runtime.h>
#include <hip/hip_fp16.h>

typedef _Float16 f16;
typedef _Float16 f16x8 __attribute__((ext_vector_type(8)));
typedef float f32x4 __attribute__((ext_vector_type(4)));

#define N_NODES 50000
#define N_EDGES 600000
#define G_GRAPHS 128
#define H 128
#define NP 50176              // 196*256, padded node count for scan
#define NT_E 18750            // 600000/32 exact
#define NB_E 1024             // edge-kernel grid (8*128 for XCD remap)
#define NT_N 1563             // ceil(50000/32)

// ---------------------------------------------------------------------------
// f0 = relu(node_f @ W_in + b_in)  -> fh (f16)
// ---------------------------------------------------------------------------
__global__ void k_f0(const float* __restrict__ node_f, const float* __restrict__ W_in,
                     const float* __restrict__ b_in, f16* __restrict__ fh)
{
    __shared__ float sW[32 * 128];
    __shared__ float sx[8][32];
    const int tid = threadIdx.x;     // 128 threads
    const int base = blockIdx.x * 8;
    for (int i = tid; i < 32 * 128; i += 128) sW[i] = W_in[i];
    for (int i = tid; i < 8 * 32; i += 128) {
        int u = i >> 5, k = i & 31;
        int n = base + u;
        sx[u][k] = (n < N_NODES) ? node_f[(size_t)n * 32 + k] : 0.0f;
    }
    __syncthreads();
    const float bj = b_in[tid];
    #pragma unroll
    for (int u = 0; u < 8; ++u) {
        int n = base + u;
        if (n >= N_NODES) break;
        float acc = bj;
        #pragma unroll
        for (int k = 0; k < 32; ++k) acc = fmaf(sx[u][k], sW[k * 128 + tid], acc);
        fh[(size_t)n * H + tid] = (f16)fmaxf(acc, 0.0f);
    }
}

// ---------------------------------------------------------------------------
// CSR build: histogram, scan, idx scatter, sequential gather (dst-sorted perm)
// ---------------------------------------------------------------------------
__global__ void k_hist(const int* __restrict__ dst, int* __restrict__ cnt)
{
    int e = blockIdx.x * 256 + threadIdx.x;
    if (e < N_EDGES) atomicAdd(&cnt[dst[e]], 1);
}

__global__ void k_scanA(const int* __restrict__ cnt, int* __restrict__ rowptr,
                        int* __restrict__ bsum)
{
    __shared__ int s[256];
    const int t = threadIdx.x;
    const int i = blockIdx.x * 256 + t;
    int v = cnt[i];
    s[t] = v;
    __syncthreads();
    #pragma unroll
    for (int off = 1; off < 256; off <<= 1) {
        int x = (t >= off) ? s[t - off] : 0;
        __syncthreads();
        s[t] += x;
        __syncthreads();
    }
    rowptr[i] = s[t] - v;
    if (t == 255) bsum[blockIdx.x] = s[255];
}

__global__ void k_scanB(const int* __restrict__ bsum, int* __restrict__ boff)
{
    __shared__ int s[256];
    const int t = threadIdx.x;
    int v = (t < 196) ? bsum[t] : 0;
    s[t] = v;
    __syncthreads();
    #pragma unroll
    for (int off = 1; off < 256; off <<= 1) {
        int x = (t >= off) ? s[t - off] : 0;
        __syncthreads();
        s[t] += x;
        __syncthreads();
    }
    boff[t] = s[t] - v;
}

__global__ void k_scanC(int* __restrict__ rowptr, const int* __restrict__ boff)
{
    int i = blockIdx.x * 256 + threadIdx.x;
    rowptr[i] += boff[blockIdx.x];
}

__global__ void k_scatter_idx(const int* __restrict__ dst, const int* __restrict__ rowptr,
                              int* __restrict__ fill, int* __restrict__ perm_eidx)
{
    int e = blockIdx.x * 256 + threadIdx.x;
    if (e >= N_EDGES) return;
    int d = dst[e];
    int p = rowptr[d] + atomicAdd(&fill[d], 1);
    perm_eidx[p] = e;
}

__global__ void k_gather(const int* __restrict__ perm_eidx, const float* __restrict__ edge_w,
                         const int* __restrict__ src, const int* __restrict__ dst,
                         const float* __restrict__ node_x,
                         int* __restrict__ perm_src, int* __restrict__ perm_dst,
                         float* __restrict__ perm_sq, f16* __restrict__ perm_ewh)
{
    int pp = blockIdx.x * 256 + threadIdx.x;
    if (pp >= N_EDGES) return;
    int e = perm_eidx[pp];
    int s = src[e], d = dst[e];
    float dx = node_x[s * 3 + 0] - node_x[d * 3 + 0];
    float dy = node_x[s * 3 + 1] - node_x[d * 3 + 1];
    float dz = node_x[s * 3 + 2] - node_x[d * 3 + 2];
    perm_src[pp] = s;
    perm_dst[pp] = d;
    perm_sq[pp] = dx * dx + dy * dy + dz * dz;
    const float4* pw = (const float4*)(edge_w + (size_t)e * 16);
    float4 w0 = pw[0], w1 = pw[1], w2 = pw[2], w3 = pw[3];
    f16x8 v0, v1;
    v0[0] = (f16)w0.x; v0[1] = (f16)w0.y; v0[2] = (f16)w0.z; v0[3] = (f16)w0.w;
    v0[4] = (f16)w1.x; v0[5] = (f16)w1.y; v0[6] = (f16)w1.z; v0[7] = (f16)w1.w;
    v1[0] = (f16)w2.x; v1[1] = (f16)w2.y; v1[2] = (f16)w2.z; v1[3] = (f16)w2.w;
    v1[4] = (f16)w3.x; v1[5] = (f16)w3.y; v1[6] = (f16)w3.z; v1[7] = (f16)w3.w;
    f16x8* q = (f16x8*)(perm_ewh + (size_t)pp * 16);
    q[0] = v0; q[1] = v1;
}

// ---------------------------------------------------------------------------
// Per-layer node projections: Gs = fh @ W1[0:128], Gd = fh @ W1[128:256]
// (no bias — b1 is added in the edge kernel's C-init)
// ---------------------------------------------------------------------------
__global__ __launch_bounds__(256, 3) void k_proj(
    const f16* __restrict__ fh, const float* __restrict__ W1,
    f16* __restrict__ Gs, f16* __restrict__ Gd)
{
    const int tid = threadIdx.x;
    const int wave = tid >> 6;       // 0..3
    const int lane = tid & 63;
    const int l16 = lane & 15;
    const int lq = lane >> 4;
    const int colbase = wave * 32;

    f16x8 wsa[4][2], wsb[4][2];
    #pragma unroll
    for (int nt = 0; nt < 2; ++nt) {
        const int col = colbase + nt * 16 + l16;
        #pragma unroll
        for (int k = 0; k < 4; ++k) {
            f16x8 va, vb;
            #pragma unroll
            for (int j = 0; j < 8; ++j) {
                va[j] = (f16)W1[(size_t)(k * 32 + lq * 8 + j) * H + col];
                vb[j] = (f16)W1[(size_t)(128 + k * 32 + lq * 8 + j) * H + col];
            }
            wsa[k][nt] = va;
            wsb[k][nt] = vb;
        }
    }

    __shared__ alignas(16) f16 U[32][136];
    const int row = tid >> 3, ch = tid & 7;

    int tile = blockIdx.x;
    f16x8 rf0, rf1;
    if (tile < NT_N) {
        int n = min(tile * 32 + row, N_NODES - 1);
        const f16x8* pf = (const f16x8*)(fh + (size_t)n * H) + ch * 2;
        rf0 = pf[0]; rf1 = pf[1];
    }
    for (; tile < NT_N; tile += gridDim.x) {
        const int n0 = tile * 32;
        {
            int4* q0 = (int4*)(&U[row][ch * 16]);
            q0[0] = *(const int4*)&rf0;
            q0[1] = *(const int4*)&rf1;
        }
        {
            int nt_ = tile + gridDim.x;
            if (nt_ < NT_N) {
                int n = min(nt_ * 32 + row, N_NODES - 1);
                const f16x8* pf = (const f16x8*)(fh + (size_t)n * H) + ch * 2;
                rf0 = pf[0]; rf1 = pf[1];
            }
        }
        __syncthreads();   // B1

        f32x4 accs[2][2], accd[2][2];
        #pragma unroll
        for (int m = 0; m < 2; ++m)
            #pragma unroll
            for (int nt = 0; nt < 2; ++nt) {
                f32x4 z = {0.0f, 0.0f, 0.0f, 0.0f};
                accs[m][nt] = z; accd[m][nt] = z;
            }
        #pragma unroll
        for (int k = 0; k < 4; ++k) {
            #pragma unroll
            for (int m = 0; m < 2; ++m) {
                f16x8 a = *(const f16x8*)&U[m * 16 + l16][k * 32 + lq * 8];
                #pragma unroll
                for (int nt = 0; nt < 2; ++nt) {
                    accs[m][nt] = __builtin_amdgcn_mfma_f32_16x16x32_f16(a, wsa[k][nt], accs[m][nt], 0, 0, 0);
                    accd[m][nt] = __builtin_amdgcn_mfma_f32_16x16x32_f16(a, wsb[k][nt], accd[m][nt], 0, 0, 0);
                }
            }
        }
        #pragma unroll
        for (int m = 0; m < 2; ++m)
            #pragma unroll
            for (int nt = 0; nt < 2; ++nt)
                #pragma unroll
                for (int r = 0; r < 4; ++r) {
                    int rr = m * 16 + lq * 4 + r;
                    int n = n0 + rr;
                    if (n < N_NODES) {
                        int col = colbase + nt * 16 + l16;
                        Gs[(size_t)n * H + col] = (f16)accs[m][nt][r];
                        Gd[(size_t)n * H + col] = (f16)accd[m][nt][r];
                    }
                }
        __syncthreads();   // B2 (U reused next iteration)
    }
}

// ---------------------------------------------------------------------------
// Edge-parallel message kernel, dst-sorted 32-edge tiles, ONE barrier/tile,
// with per-node projections as C-init:
//   h1 = relu( Gs[src] + Gd[dst] + w@W1c + sq*w1last + b1 ),  w = relu(ew@We+be)
// Section t: C-init from Gt[pa] + dc/sq -> issue Gs/Gd/ewh loads(t+1) +
//   meta(t+2) -> mm2(t-1)+atomics(t-1) -> mm1-w(t)->h1B[pa] ->
//   weMFMA(t+1)->Atile[pa^1] -> Gsum(t+1)->Gt[pa^1] -> meta->LDS -> barrier.
// VGPR cap 128 ((512,4)) — measured need ~95-105; NEVER cap below 128
// (R4/R6/R11 all spilled catastrophically at lower caps).
// Hazards: every LDS buffer's write->read crosses exactly one barrier
// (Atile/Gt: written late t, read t+1; h1B: written t, read t+1; meta slots
// distinct mod 3). dcp is a wave-private register carry.
// ---------------------------------------------------------------------------
__global__ __launch_bounds__(512, 4) void k_edge2(
    const f16* __restrict__ Gs, const f16* __restrict__ Gd,
    const int* __restrict__ perm_src, const int* __restrict__ perm_dst,
    const float* __restrict__ perm_sq, const f16* __restrict__ perm_ewh,
    const float* __restrict__ W_e, const float* __restrict__ b_e,
    const float* __restrict__ W1, const float* __restrict__ b1,
    const float* __restrict__ W2, const float* __restrict__ b2,
    f16* __restrict__ msum)
{
    const int tid = threadIdx.x;
    const int wave = tid >> 6;
    const int lane = tid & 63;
    const int l16 = lane & 15;
    const int lq  = lane >> 4;
    const int col = wave * 16 + l16;

    f16x8 wef, w1f[4], w2f[4];
    #pragma unroll
    for (int j = 0; j < 8; ++j) {
        int k = lq * 8 + j;
        wef[j] = (k < 16) ? (f16)W_e[(size_t)k * H + col] : (f16)0.0f;
    }
    #pragma unroll
    for (int k = 0; k < 4; ++k)
        #pragma unroll
        for (int j = 0; j < 8; ++j) {
            w1f[k][j] = (f16)W1[(size_t)(256 + k * 32 + lq * 8 + j) * H + col];
            w2f[k][j] = (f16)W2[(size_t)(k * 32 + lq * 8 + j) * H + col];
        }
    const float w1last = W1[(size_t)384 * H + col];
    const float b1v = b1[col], b2v = b2[col], bev = b_e[col];

    __shared__ alignas(16) f16 Atile[2][32][136];   // w cols only, 17.4 KB
    __shared__ alignas(16) f16 h1B[2][32][136];     // 17.4 KB
    __shared__ alignas(16) f16 Gt[2][32][136];      // Gs[src]+Gd[dst], 17.4 KB
    __shared__ int   s_src[3][32];
    __shared__ int   s_dst[3][32];
    __shared__ float s_sq[3][32];

    const int b = ((blockIdx.x & 7) << 7) | (blockIdx.x >> 3);
    const int t0 = (int)((long)b * NT_E / NB_E);
    const int t1 = (int)((long)(b + 1) * NT_E / NB_E);

    const int srow = tid >> 4, sch = tid & 15;
    const int sj = ((srow >> 2) & 3) * 8 + ((srow >> 4) << 2) + (srow & 3); // eperm

    // ---- prologue ----
    if (tid < 32) {
        int e0 = t0 * 32 + tid;
        s_src[t0 % 3][tid] = perm_src[e0];
        s_dst[t0 % 3][tid] = perm_dst[e0];
        s_sq [t0 % 3][tid] = perm_sq[e0];
        int e1 = min((t0 + 1) * 32 + tid, N_EDGES - 1);
        s_src[(t0 + 1) % 3][tid] = perm_src[e1];
        s_dst[(t0 + 1) % 3][tid] = perm_dst[e1];
        s_sq [(t0 + 1) % 3][tid] = perm_sq[e1];
    }
    __syncthreads();
    {
        const int pa = t0 & 1;
        int sv = s_src[t0 % 3][sj], dv = s_dst[t0 % 3][sj];
        union { int4 i; f16x8 h; } ua, ub, uo;
        ua.i = ((const int4*)(Gs + (size_t)sv * H))[sch];
        ub.i = ((const int4*)(Gd + (size_t)dv * H))[sch];
        #pragma unroll
        for (int j = 0; j < 8; ++j) uo.h[j] = (f16)((float)ua.h[j] + (float)ub.h[j]);
        ((int4*)&Gt[pa][srow][0])[sch] = uo.i;
        #pragma unroll
        for (int m = 0; m < 2; ++m) {
            f16x8 aa;
            if (lq < 2) {
                int j = (l16 >> 2) * 8 + m * 4 + (l16 & 3);
                aa = *(const f16x8*)(perm_ewh + (size_t)(t0 * 32 + j) * 16 + lq * 8);
            } else {
                #pragma unroll
                for (int jj = 0; jj < 8; ++jj) aa[jj] = (f16)0.0f;
            }
            f32x4 c = {bev, bev, bev, bev};
            c = __builtin_amdgcn_mfma_f32_16x16x32_f16(aa, wef, c, 0, 0, 0);
            #pragma unroll
            for (int r = 0; r < 4; ++r)
                Atile[pa][m * 16 + lq * 4 + r][col] = (f16)fmaxf(c[r], 0.0f);
        }
    }
    __syncthreads();

    int dcp[8];
    for (int t = t0; t < t1; ++t) {
        const int pa = t & 1;
        const int m0 = t % 3;
        const int m1 = (t + 1) % 3;
        const int m2 = (t + 2) % 3;

        // 1. dc(t), C-init: b1 + sq*w1last + Gsum
        int dc[8];
        f32x4 acc1[2];
        #pragma unroll
        for (int m = 0; m < 2; ++m)
            #pragma unroll
            for (int r = 0; r < 4; ++r) {
                int j = lq * 8 + m * 4 + r;
                int row = m * 16 + lq * 4 + r;
                dc[m * 4 + r] = s_dst[m0][j];
                acc1[m][r] = fmaf(s_sq[m0][j], w1last, b1v) + (float)Gt[pa][row][col];
            }

        // 2. issue Gs/Gd/ewh loads for tile t+1
        int4 ga_, gb_;
        f16x8 rew[2];
        {
            int sv = s_src[m1][sj], dv = s_dst[m1][sj];
            ga_ = ((const int4*)(Gs + (size_t)sv * H))[sch];
            gb_ = ((const int4*)(Gd + (size_t)dv * H))[sch];
            #pragma unroll
            for (int m = 0; m < 2; ++m) {
                if (lq < 2) {
                    int j = (l16 >> 2) * 8 + m * 4 + (l16 & 3);
                    int e = min((t + 1) * 32 + j, N_EDGES - 1);
                    rew[m] = *(const f16x8*)(perm_ewh + (size_t)e * 16 + lq * 8);
                }
            }
        }
        // 3. meta(t+2)
        int mrs = 0, mrd = 0; float mrq = 0.0f;
        if (tid < 32) {
            int e = min((t + 2) * 32 + tid, N_EDGES - 1);
            mrs = perm_src[e]; mrd = perm_dst[e]; mrq = perm_sq[e];
        }

        // 4+5. mm2(t-1) + atomics
        if (t > t0) {
            f32x4 acc2[2];
            #pragma unroll
            for (int m = 0; m < 2; ++m) {
                f32x4 c = {b2v, b2v, b2v, b2v};
                acc2[m] = c;
            }
            #pragma unroll
            for (int k = 0; k < 4; ++k) {
                #pragma unroll
                for (int m = 0; m < 2; ++m) {
                    f16x8 a = *(const f16x8*)&h1B[pa ^ 1][m * 16 + l16][k * 32 + lq * 8];
                    acc2[m] = __builtin_amdgcn_mfma_f32_16x16x32_f16(a, w2f[k], acc2[m], 0, 0, 0);
                }
            }
            float run = fmaxf(acc2[0][0], 0.0f);
            int cd = dcp[0];
            #pragma unroll
            for (int i = 1; i < 8; ++i) {
                float v = fmaxf(acc2[i >> 2][i & 3], 0.0f);
                int d = dcp[i];
                if (d == cd) {
                    run += v;
                } else {
                    float nb = __shfl_xor(run, 1);
                    if ((l16 & 1) == 0) {
                        union { f16 h[2]; __half2 v2; } u;
                        u.h[0] = (f16)run; u.h[1] = (f16)nb;
                        unsafeAtomicAdd((__half2*)&msum[(size_t)cd * H + col], u.v2);
                    }
                    run = v; cd = d;
                }
            }
            float nb = __shfl_xor(run, 1);
            if ((l16 & 1) == 0) {
                union { f16 h[2]; __half2 v2; } u;
                u.h[0] = (f16)run; u.h[1] = (f16)nb;
                unsafeAtomicAdd((__half2*)&msum[(size_t)cd * H + col], u.v2);
            }
        }

        // 6. mm1-w(t) -> h1B[pa]
        #pragma unroll
        for (int k = 0; k < 4; ++k) {
            #pragma unroll
            for (int m = 0; m < 2; ++m) {
                f16x8 a = *(const f16x8*)&Atile[pa][m * 16 + l16][k * 32 + lq * 8];
                acc1[m] = __builtin_amdgcn_mfma_f32_16x16x32_f16(a, w1f[k], acc1[m], 0, 0, 0);
            }
        }
        #pragma unroll
        for (int m = 0; m < 2; ++m)
            #pragma unroll
            for (int r = 0; r < 4; ++r)
                h1B[pa][m * 16 + lq * 4 + r][col] = (f16)fmaxf(acc1[m][r], 0.0f);

        // 7. we-MFMA(t+1) -> Atile[pa^1]
        #pragma unroll
        for (int m = 0; m < 2; ++m) {
            f16x8 aa;
            if (lq < 2) {
                aa = rew[m];
            } else {
                #pragma unroll
                for (int jj = 0; jj < 8; ++jj) aa[jj] = (f16)0.0f;
            }
            f32x4 c = {bev, bev, bev, bev};
            c = __builtin_amdgcn_mfma_f32_16x16x32_f16(aa, wef, c, 0, 0, 0);
            #pragma unroll
            for (int r = 0; r < 4; ++r)
                Atile[pa ^ 1][m * 16 + lq * 4 + r][col] = (f16)fmaxf(c[r], 0.0f);
        }
        // 8. Gsum(t+1) -> Gt[pa^1]
        {
            union { int4 i; f16x8 h; } ua, ub, uo;
            ua.i = ga_; ub.i = gb_;
            #pragma unroll
            for (int j = 0; j < 8; ++j) uo.h[j] = (f16)((float)ua.h[j] + (float)ub.h[j]);
            ((int4*)&Gt[pa ^ 1][srow][0])[sch] = uo.i;
        }
        // 9. meta(t+2) -> LDS
        if (tid < 32) {
            s_src[m2][tid] = mrs; s_dst[m2][tid] = mrd; s_sq[m2][tid] = mrq;
        }
        // 10. carry dc
        #pragma unroll
        for (int i = 0; i < 8; ++i) dcp[i] = dc[i];
        __syncthreads();
    }

    // ---- epilogue: mm2(t1-1) + atomics ----
    {
        const int ph = (t1 - 1) & 1;
        f32x4 acc2[2];
        #pragma unroll
        for (int m = 0; m < 2; ++m) {
            f32x4 c = {b2v, b2v, b2v, b2v};
            acc2[m] = c;
        }
        #pragma unroll
        for (int k = 0; k < 4; ++k) {
            #pragma unroll
            for (int m = 0; m < 2; ++m) {
                f16x8 a = *(const f16x8*)&h1B[ph][m * 16 + l16][k * 32 + lq * 8];
                acc2[m] = __builtin_amdgcn_mfma_f32_16x16x32_f16(a, w2f[k], acc2[m], 0, 0, 0);
            }
        }
        float run = fmaxf(acc2[0][0], 0.0f);
        int cd = dcp[0];
        #pragma unroll
        for (int i = 1; i < 8; ++i) {
            float v = fmaxf(acc2[i >> 2][i & 3], 0.0f);
            int d = dcp[i];
            if (d == cd) {
                run += v;
            } else {
                float nb = __shfl_xor(run, 1);
                if ((l16 & 1) == 0) {
                    union { f16 h[2]; __half2 v2; } u;
                    u.h[0] = (f16)run; u.h[1] = (f16)nb;
                    unsafeAtomicAdd((__half2*)&msum[(size_t)cd * H + col], u.v2);
                }
                run = v; cd = d;
            }
        }
        float nb = __shfl_xor(run, 1);
        if ((l16 & 1) == 0) {
            union { f16 h[2]; __half2 v2; } u;
            u.h[0] = (f16)run; u.h[1] = (f16)nb;
            unsafeAtomicAdd((__half2*)&msum[(size_t)cd * H + col], u.v2);
        }
    }
}

// ---------------------------------------------------------------------------
// Node update: fh = relu(relu((msum+fh)@U1+b1)@U2+b2), pipelined, 2 barriers.
// ---------------------------------------------------------------------------
__global__ __launch_bounds__(256, 3) void k_update(
    const f16* __restrict__ msum, f16* __restrict__ fh,
    const float* __restrict__ W1, const float* __restrict__ b1,
    const float* __restrict__ W2, const float* __restrict__ b2)
{
    const int tid = threadIdx.x;
    const int wave = tid >> 6;       // 0..3
    const int lane = tid & 63;
    const int l16 = lane & 15;
    const int lq = lane >> 4;
    const int colbase = wave * 32;

    f16x8 w1fr[4][2], w2fr[4][2];
    float b1v[2], b2v[2];
    #pragma unroll
    for (int nt = 0; nt < 2; ++nt) {
        const int col = colbase + nt * 16 + l16;
        #pragma unroll
        for (int k = 0; k < 4; ++k) {
            f16x8 v1, v2;
            #pragma unroll
            for (int j = 0; j < 8; ++j) {
                v1[j] = (f16)W1[(size_t)(k * 32 + lq * 8 + j) * H + col];
                v2[j] = (f16)W2[(size_t)(k * 32 + lq * 8 + j) * H + col];
            }
            w1fr[k][nt] = v1;
            w2fr[k][nt] = v2;
        }
        b1v[nt] = b1[col];
        b2v[nt] = b2[col];
    }

    __shared__ alignas(16) f16 U[32][136];
    __shared__ alignas(16) f16 h1b[32][136];
    const int row = tid >> 3, ch = tid & 7;

    int tile = blockIdx.x;
    f16x8 rm0, rm1, rf0, rf1;
    if (tile < NT_N) {
        int n = min(tile * 32 + row, N_NODES - 1);
        const f16x8* pm = (const f16x8*)(msum + (size_t)n * H) + ch * 2;
        const f16x8* pf = (const f16x8*)(fh + (size_t)n * H) + ch * 2;
        rm0 = pm[0]; rm1 = pm[1]; rf0 = pf[0]; rf1 = pf[1];
    }
    for (; tile < NT_N; tile += gridDim.x) {
        const int n0 = tile * 32;
        {
            f16 tmp[16];
            #pragma unroll
            for (int j = 0; j < 8; ++j) {
                tmp[j]     = (f16)((float)rm0[j] + (float)rf0[j]);
                tmp[8 + j] = (f16)((float)rm1[j] + (float)rf1[j]);
            }
            int4* q0 = (int4*)(&U[row][ch * 16]);
            q0[0] = ((const int4*)tmp)[0];
            q0[1] = ((const int4*)tmp)[1];
        }
        {
            int nt_ = tile + gridDim.x;
            if (nt_ < NT_N) {
                int n = min(nt_ * 32 + row, N_NODES - 1);
                const f16x8* pm = (const f16x8*)(msum + (size_t)n * H) + ch * 2;
                const f16x8* pf = (const f16x8*)(fh + (size_t)n * H) + ch * 2;
                rm0 = pm[0]; rm1 = pm[1]; rf0 = pf[0]; rf1 = pf[1];
            }
        }
        __syncthreads();   // B1

        f32x4 acc[2][2];
        #pragma unroll
        for (int m = 0; m < 2; ++m)
            #pragma unroll
            for (int nt = 0; nt < 2; ++nt) {
                f32x4 c = {b1v[nt], b1v[nt], b1v[nt], b1v[nt]};
                acc[m][nt] = c;
            }
        #pragma unroll
        for (int k = 0; k < 4; ++k) {
            #pragma unroll
            for (int m = 0; m < 2; ++m) {
                f16x8 a = *(const f16x8*)&U[m * 16 + l16][k * 32 + lq * 8];
                #pragma unroll
                for (int nt = 0; nt < 2; ++nt)
                    acc[m][nt] = __builtin_amdgcn_mfma_f32_16x16x32_f16(a, w1fr[k][nt], acc[m][nt], 0, 0, 0);
            }
        }
        #pragma unroll
        for (int m = 0; m < 2; ++m)
            #pragma unroll
            for (int nt = 0; nt < 2; ++nt)
                #pragma unroll
                for (int r = 0; r < 4; ++r)
                    h1b[m * 16 + lq * 4 + r][colbase + nt * 16 + l16] = (f16)fmaxf(acc[m][nt][r], 0.0f);
        __syncthreads();   // B2

        f32x4 acc2[2][2];
        #pragma unroll
        for (int m = 0; m < 2; ++m)
            #pragma unroll
            for (int nt = 0; nt < 2; ++nt) {
                f32x4 c = {b2v[nt], b2v[nt], b2v[nt], b2v[nt]};
                acc2[m][nt] = c;
            }
        #pragma unroll
        for (int k = 0; k < 4; ++k) {
            #pragma unroll
            for (int m = 0; m < 2; ++m) {
                f16x8 a = *(const f16x8*)&h1b[m * 16 + l16][k * 32 + lq * 8];
                #pragma unroll
                for (int nt = 0; nt < 2; ++nt)
                    acc2[m][nt] = __builtin_amdgcn_mfma_f32_16x16x32_f16(a, w2fr[k][nt], acc2[m][nt], 0, 0, 0);
            }
        }
        #pragma unroll
        for (int m = 0; m < 2; ++m)
            #pragma unroll
            for (int nt = 0; nt < 2; ++nt)
                #pragma unroll
                for (int r = 0; r < 4; ++r) {
                    int rr = m * 16 + lq * 4 + r;
                    int n = n0 + rr;
                    if (n < N_NODES)
                        fh[(size_t)n * H + colbase + nt * 16 + l16] = (f16)fmaxf(acc2[m][nt][r], 0.0f);
                }
    }
}

// ---------------------------------------------------------------------------
// Per-graph mean/max readout (graph_ids sorted; f >= 0)
// ---------------------------------------------------------------------------
__global__ void k_readout(const f16* __restrict__ fh, const int* __restrict__ gid,
                          float* __restrict__ gsum, float* __restrict__ gmax,
                          int* __restrict__ gcnt)
{
    __shared__ int s_gid[64];
    const int tid = threadIdx.x;            // 128 threads
    const int base = blockIdx.x * 64;
    if (tid < 64) s_gid[tid] = (base + tid < N_NODES) ? gid[base + tid] : -1;
    __syncthreads();
    if (tid < 64 && base + tid < N_NODES) atomicAdd(&gcnt[s_gid[tid]], 1);

    float lsum = 0.0f, lmax = 0.0f;
    int cur = s_gid[0];
    if (cur >= 0) {
        for (int i = 0; i < 64; ++i) {
            int g = s_gid[i];
            if (g < 0) break;
            if (g != cur) {
                unsafeAtomicAdd(&gsum[(size_t)cur * H + tid], lsum);
                atomicMax((int*)&gmax[(size_t)cur * H + tid], __float_as_int(lmax));
                lsum = 0.0f; lmax = 0.0f; cur = g;
            }
            float v = (float)fh[(size_t)(base + i) * H + tid];
            lsum += v;
            lmax = fmaxf(lmax, v);
        }
        unsafeAtomicAdd(&gsum[(size_t)cur * H + tid], lsum);
        atomicMax((int*)&gmax[(size_t)cur * H + tid], __float_as_int(lmax));
    }
}

__global__ void k_out(const float* __restrict__ gsum, const float* __restrict__ gmax,
                      const int* __restrict__ gcnt, const float* __restrict__ W_out,
                      const float* __restrict__ b_out, float* __restrict__ out)
{
    __shared__ float sm[128], sx[128];
    const int g = blockIdx.x, t = threadIdx.x;
    const float inv = 1.0f / fmaxf((float)gcnt[g], 1.0f);
    sm[t] = gsum[(size_t)g * H + t] * inv;
    sx[t] = gmax[(size_t)g * H + t];
    __syncthreads();
    float acc = b_out[t];
    for (int k = 0; k < H; ++k) {
        acc = fmaf(sm[k], W_out[(size_t)k * 128 + t], acc);
        acc = fmaf(sx[k], W_out[(size_t)(128 + k) * 128 + t], acc);
    }
    out[(size_t)g * 128 + t] = acc;
}

// ---------------------------------------------------------------------------
extern "C" void kernel_launch(void* const* d_in, const int* in_sizes, int n_in,
                              void* d_out, int out_size, void* d_ws, size_t ws_size,
                              hipStream_t stream)
{
    const float* node_f = (const float*)d_in[0];
    const float* node_x = (const float*)d_in[1];
    const float* edge_w = (const float*)d_in[2];
    const int*   src    = (const int*)d_in[3];
    const int*   dst    = (const int*)d_in[4];
    const int*   gid    = (const int*)d_in[5];
    const float* W_in   = (const float*)d_in[6];
    const float* b_in   = (const float*)d_in[7];
    const float* W_e    = (const float*)d_in[8];
    const float* b_e    = (const float*)d_in[9];
    const float* msg_W1 = (const float*)d_in[10];
    const float* msg_b1 = (const float*)d_in[11];
    const float* msg_W2 = (const float*)d_in[12];
    const float* msg_b2 = (const float*)d_in[13];
    const float* upd_W1 = (const float*)d_in[14];
    const float* upd_b1 = (const float*)d_in[15];
    const float* upd_W2 = (const float*)d_in[16];
    const float* upd_b2 = (const float*)d_in[17];
    const float* W_out  = (const float*)d_in[18];
    const float* b_out  = (const float*)d_in[19];
    float* out = (float*)d_out;

    char* ws = (char*)d_ws;
    size_t off = 0;
    f16*   fh       = (f16*)(ws + off);   off += (size_t)N_NODES * H * 2;      // 12.8 MB
    f16*   Gs       = (f16*)(ws + off);   off += (size_t)N_NODES * H * 2;      // 12.8 MB
    f16*   Gd       = (f16*)(ws + off);   off += (size_t)N_NODES * H * 2;      // 12.8 MB
    f16*   perm_ewh = (f16*)(ws + off);   off += (size_t)N_EDGES * 16 * 2;     // 19.2 MB
    int*   perm_src = (int*)(ws + off);   off += (size_t)N_EDGES * 4;          // 2.4 MB
    int*   perm_dst = (int*)(ws + off);   off += (size_t)N_EDGES * 4;          // 2.4 MB
    float* perm_sq  = (float*)(ws + off); off += (size_t)N_EDGES * 4;          // 2.4 MB
    int*   rowptr   = (int*)(ws + off);   off += (size_t)NP * 4;
    int*   cnt      = (int*)(ws + off);   off += (size_t)NP * 4;               // also 'fill'
    int*   bsum     = (int*)(ws + off);   off += 256 * 4;
    int*   boff     = (int*)(ws + off);   off += 256 * 4;
    f16*   msum     = (f16*)(ws + off);   off += (size_t)N_NODES * H * 2;      // 12.8 MB
    float* gsum     = (float*)(ws + off); off += (size_t)G_GRAPHS * H * 4;
    float* gmax     = (float*)(ws + off); off += (size_t)G_GRAPHS * H * 4;
    int*   gcnt     = (int*)(ws + off);   off += (size_t)G_GRAPHS * 4;
    int*   perm_eidx = (int*)msum;        // aliased: eidx only used pre-layers

    k_f0<<<(N_NODES + 7) / 8, 128, 0, stream>>>(node_f, W_in, b_in, fh);

    (void)hipMemsetAsync(cnt, 0, (size_t)NP * 4, stream);
    k_hist<<<(N_EDGES + 255) / 256, 256, 0, stream>>>(dst, cnt);
    k_scanA<<<NP / 256, 256, 0, stream>>>(cnt, rowptr, bsum);
    k_scanB<<<1, 256, 0, stream>>>(bsum, boff);
    k_scanC<<<NP / 256, 256, 0, stream>>>(rowptr, boff);
    (void)hipMemsetAsync(cnt, 0, (size_t)NP * 4, stream);
    k_scatter_idx<<<(N_EDGES + 255) / 256, 256, 0, stream>>>(dst, rowptr, cnt, perm_eidx);
    k_gather<<<(N_EDGES + 255) / 256, 256, 0, stream>>>(perm_eidx, edge_w, src, dst, node_x,
                                                        perm_src, perm_dst, perm_sq, perm_ewh);

    for (int l = 0; l < 4; ++l) {
        (void)hipMemsetAsync(msum, 0, (size_t)N_NODES * H * 2, stream);
        k_proj<<<512, 256, 0, stream>>>(fh, msg_W1 + (size_t)l * 385 * H, Gs, Gd);
        k_edge2<<<NB_E, 512, 0, stream>>>(Gs, Gd, perm_src, perm_dst, perm_sq, perm_ewh,
                                          W_e, b_e,
                                          msg_W1 + (size_t)l * 385 * H, msg_b1 + (size_t)l * H,
                                          msg_W2 + (size_t)l * H * H,  msg_b2 + (size_t)l * H,
                                          msum);
        k_update<<<512, 256, 0, stream>>>(msum, fh,
                                          upd_W1 + (size_t)l * H * H, upd_b1 + (size_t)l * H,
                                          upd_W2 + (size_t)l * H * H, upd_b2 + (size_t)l * H);
    }

    (void)hipMemsetAsync(gsum, 0, (size_t)G_GRAPHS * H * 4, stream);
    (void)hipMemsetAsync(gmax, 0, (size_t)G_GRAPHS * H * 4, stream);
    (void)hipMemsetAsync(gcnt, 0, (size_t)G_GRAPHS * 4, stream);
    k_readout<<<(N_NODES + 63) / 64, 128, 0, stream>>>(fh, gid, gsum, gmax, gcnt);
    k_out<<<G_GRAPHS, 128, 0, stream>>>(gsum, gmax, gcnt, W_out, b_out, out);
}

// Round 13
// 1201.324 us; speedup vs baseline: 2.0011x; 1.1933x over previous
//
#include <hip/hip_runtime.h>
#include <hip/hip_fp16.h>

typedef _Float16 f16;
typedef _Float16 f16x8 __attribute__((ext_vector_type(8)));
typedef float f32x4 __attribute__((ext_vector_type(4)));

#define N_NODES 50000
#define N_EDGES 600000
#define G_GRAPHS 128
#define H 128
#define NP 50176              // 196*256, padded node count for scan
#define NT_E 18750            // 600000/32 exact
#define NB_E 1024             // edge-kernel grid (8*128 for XCD remap)
#define NT_N 1563             // ceil(50000/32)

// ---------------------------------------------------------------------------
// f0 = relu(node_f @ W_in + b_in)  -> fh (f16)
// ---------------------------------------------------------------------------
__global__ void k_f0(const float* __restrict__ node_f, const float* __restrict__ W_in,
                     const float* __restrict__ b_in, f16* __restrict__ fh)
{
    __shared__ float sW[32 * 128];
    __shared__ float sx[8][32];
    const int tid = threadIdx.x;     // 128 threads
    const int base = blockIdx.x * 8;
    for (int i = tid; i < 32 * 128; i += 128) sW[i] = W_in[i];
    for (int i = tid; i < 8 * 32; i += 128) {
        int u = i >> 5, k = i & 31;
        int n = base + u;
        sx[u][k] = (n < N_NODES) ? node_f[(size_t)n * 32 + k] : 0.0f;
    }
    __syncthreads();
    const float bj = b_in[tid];
    #pragma unroll
    for (int u = 0; u < 8; ++u) {
        int n = base + u;
        if (n >= N_NODES) break;
        float acc = bj;
        #pragma unroll
        for (int k = 0; k < 32; ++k) acc = fmaf(sx[u][k], sW[k * 128 + tid], acc);
        fh[(size_t)n * H + tid] = (f16)fmaxf(acc, 0.0f);
    }
}

// ---------------------------------------------------------------------------
// CSR build: histogram, scan, idx scatter, sequential gather (dst-sorted perm)
// ---------------------------------------------------------------------------
__global__ void k_hist(const int* __restrict__ dst, int* __restrict__ cnt)
{
    int e = blockIdx.x * 256 + threadIdx.x;
    if (e < N_EDGES) atomicAdd(&cnt[dst[e]], 1);
}

__global__ void k_scanA(const int* __restrict__ cnt, int* __restrict__ rowptr,
                        int* __restrict__ bsum)
{
    __shared__ int s[256];
    const int t = threadIdx.x;
    const int i = blockIdx.x * 256 + t;
    int v = cnt[i];
    s[t] = v;
    __syncthreads();
    #pragma unroll
    for (int off = 1; off < 256; off <<= 1) {
        int x = (t >= off) ? s[t - off] : 0;
        __syncthreads();
        s[t] += x;
        __syncthreads();
    }
    rowptr[i] = s[t] - v;
    if (t == 255) bsum[blockIdx.x] = s[255];
}

__global__ void k_scanB(const int* __restrict__ bsum, int* __restrict__ boff)
{
    __shared__ int s[256];
    const int t = threadIdx.x;
    int v = (t < 196) ? bsum[t] : 0;
    s[t] = v;
    __syncthreads();
    #pragma unroll
    for (int off = 1; off < 256; off <<= 1) {
        int x = (t >= off) ? s[t - off] : 0;
        __syncthreads();
        s[t] += x;
        __syncthreads();
    }
    boff[t] = s[t] - v;
}

__global__ void k_scanC(int* __restrict__ rowptr, const int* __restrict__ boff)
{
    int i = blockIdx.x * 256 + threadIdx.x;
    rowptr[i] += boff[blockIdx.x];
}

__global__ void k_scatter_idx(const int* __restrict__ dst, const int* __restrict__ rowptr,
                              int* __restrict__ fill, int* __restrict__ perm_eidx)
{
    int e = blockIdx.x * 256 + threadIdx.x;
    if (e >= N_EDGES) return;
    int d = dst[e];
    int p = rowptr[d] + atomicAdd(&fill[d], 1);
    perm_eidx[p] = e;
}

__global__ void k_gather(const int* __restrict__ perm_eidx, const float* __restrict__ edge_w,
                         const int* __restrict__ src, const int* __restrict__ dst,
                         const float* __restrict__ node_x,
                         int* __restrict__ perm_src, int* __restrict__ perm_dst,
                         float* __restrict__ perm_sq, f16* __restrict__ perm_ewh)
{
    int pp = blockIdx.x * 256 + threadIdx.x;
    if (pp >= N_EDGES) return;
    int e = perm_eidx[pp];
    int s = src[e], d = dst[e];
    float dx = node_x[s * 3 + 0] - node_x[d * 3 + 0];
    float dy = node_x[s * 3 + 1] - node_x[d * 3 + 1];
    float dz = node_x[s * 3 + 2] - node_x[d * 3 + 2];
    perm_src[pp] = s;
    perm_dst[pp] = d;
    perm_sq[pp] = dx * dx + dy * dy + dz * dz;
    const float4* pw = (const float4*)(edge_w + (size_t)e * 16);
    float4 w0 = pw[0], w1 = pw[1], w2 = pw[2], w3 = pw[3];
    f16x8 v0, v1;
    v0[0] = (f16)w0.x; v0[1] = (f16)w0.y; v0[2] = (f16)w0.z; v0[3] = (f16)w0.w;
    v0[4] = (f16)w1.x; v0[5] = (f16)w1.y; v0[6] = (f16)w1.z; v0[7] = (f16)w1.w;
    v1[0] = (f16)w2.x; v1[1] = (f16)w2.y; v1[2] = (f16)w2.z; v1[3] = (f16)w2.w;
    v1[4] = (f16)w3.x; v1[5] = (f16)w3.y; v1[6] = (f16)w3.z; v1[7] = (f16)w3.w;
    f16x8* q = (f16x8*)(perm_ewh + (size_t)pp * 16);
    q[0] = v0; q[1] = v1;
}

// ---------------------------------------------------------------------------
// Per-layer node projections: Gs = fh @ W1[0:128], Gd = fh @ W1[128:256]
// (no bias — b1 is added in the edge kernel's C-init)
// ---------------------------------------------------------------------------
__global__ __launch_bounds__(256, 3) void k_proj(
    const f16* __restrict__ fh, const float* __restrict__ W1,
    f16* __restrict__ Gs, f16* __restrict__ Gd)
{
    const int tid = threadIdx.x;
    const int wave = tid >> 6;       // 0..3
    const int lane = tid & 63;
    const int l16 = lane & 15;
    const int lq = lane >> 4;
    const int colbase = wave * 32;

    f16x8 wsa[4][2], wsb[4][2];
    #pragma unroll
    for (int nt = 0; nt < 2; ++nt) {
        const int col = colbase + nt * 16 + l16;
        #pragma unroll
        for (int k = 0; k < 4; ++k) {
            f16x8 va, vb;
            #pragma unroll
            for (int j = 0; j < 8; ++j) {
                va[j] = (f16)W1[(size_t)(k * 32 + lq * 8 + j) * H + col];
                vb[j] = (f16)W1[(size_t)(128 + k * 32 + lq * 8 + j) * H + col];
            }
            wsa[k][nt] = va;
            wsb[k][nt] = vb;
        }
    }

    __shared__ alignas(16) f16 U[32][136];
    const int row = tid >> 3, ch = tid & 7;

    int tile = blockIdx.x;
    f16x8 rf0, rf1;
    if (tile < NT_N) {
        int n = min(tile * 32 + row, N_NODES - 1);
        const f16x8* pf = (const f16x8*)(fh + (size_t)n * H) + ch * 2;
        rf0 = pf[0]; rf1 = pf[1];
    }
    for (; tile < NT_N; tile += gridDim.x) {
        const int n0 = tile * 32;
        {
            int4* q0 = (int4*)(&U[row][ch * 16]);
            q0[0] = *(const int4*)&rf0;
            q0[1] = *(const int4*)&rf1;
        }
        {
            int nt_ = tile + gridDim.x;
            if (nt_ < NT_N) {
                int n = min(nt_ * 32 + row, N_NODES - 1);
                const f16x8* pf = (const f16x8*)(fh + (size_t)n * H) + ch * 2;
                rf0 = pf[0]; rf1 = pf[1];
            }
        }
        __syncthreads();   // B1

        f32x4 accs[2][2], accd[2][2];
        #pragma unroll
        for (int m = 0; m < 2; ++m)
            #pragma unroll
            for (int nt = 0; nt < 2; ++nt) {
                f32x4 z = {0.0f, 0.0f, 0.0f, 0.0f};
                accs[m][nt] = z; accd[m][nt] = z;
            }
        #pragma unroll
        for (int k = 0; k < 4; ++k) {
            #pragma unroll
            for (int m = 0; m < 2; ++m) {
                f16x8 a = *(const f16x8*)&U[m * 16 + l16][k * 32 + lq * 8];
                #pragma unroll
                for (int nt = 0; nt < 2; ++nt) {
                    accs[m][nt] = __builtin_amdgcn_mfma_f32_16x16x32_f16(a, wsa[k][nt], accs[m][nt], 0, 0, 0);
                    accd[m][nt] = __builtin_amdgcn_mfma_f32_16x16x32_f16(a, wsb[k][nt], accd[m][nt], 0, 0, 0);
                }
            }
        }
        #pragma unroll
        for (int m = 0; m < 2; ++m)
            #pragma unroll
            for (int nt = 0; nt < 2; ++nt)
                #pragma unroll
                for (int r = 0; r < 4; ++r) {
                    int rr = m * 16 + lq * 4 + r;
                    int n = n0 + rr;
                    if (n < N_NODES) {
                        int col = colbase + nt * 16 + l16;
                        Gs[(size_t)n * H + col] = (f16)accs[m][nt][r];
                        Gd[(size_t)n * H + col] = (f16)accd[m][nt][r];
                    }
                }
        __syncthreads();   // B2 (U reused next iteration)
    }
}

// ---------------------------------------------------------------------------
// Edge-parallel message kernel, dst-sorted 32-edge tiles, ONE barrier/tile,
// with per-node projections as C-init:
//   h1 = relu( Gs[src] + Gd[dst] + w@W1c + sq*w1last + b1 ),  w = relu(ew@We+be)
// Section t: C-init from Gt[pa] + dc/sq -> issue Gs/Gd/ewh loads(t+1) +
//   meta(t+2) -> mm2(t-1)+atomics(t-1) -> mm1-w(t)->h1B[pa] ->
//   weMFMA(t+1)->Atile[pa^1] -> Gsum(t+1)->Gt[pa^1] -> meta->LDS -> barrier.
// LAUNCH BOUNDS: empirically the 2nd arg is min BLOCKS/CU (CUDA semantics),
// cap = 2048/(blocks*8) for 512-thr blocks: (512,2)->128, (512,4)->64,
// (512,6)->42 [R5/R9/R10 vs R4/R6/R12 vs R11 VGPR counts]. This kernel needs
// ~95-105 VGPR -> ONLY (512,2) is safe. Never increase the 2nd arg.
// Hazards: every LDS buffer's write->read crosses exactly one barrier
// (Atile/Gt: written late t, read t+1; h1B: written t, read t+1; meta slots
// distinct mod 3). dcp is a wave-private register carry.
// ---------------------------------------------------------------------------
__global__ __launch_bounds__(512, 2) void k_edge2(
    const f16* __restrict__ Gs, const f16* __restrict__ Gd,
    const int* __restrict__ perm_src, const int* __restrict__ perm_dst,
    const float* __restrict__ perm_sq, const f16* __restrict__ perm_ewh,
    const float* __restrict__ W_e, const float* __restrict__ b_e,
    const float* __restrict__ W1, const float* __restrict__ b1,
    const float* __restrict__ W2, const float* __restrict__ b2,
    f16* __restrict__ msum)
{
    const int tid = threadIdx.x;
    const int wave = tid >> 6;
    const int lane = tid & 63;
    const int l16 = lane & 15;
    const int lq  = lane >> 4;
    const int col = wave * 16 + l16;

    f16x8 wef, w1f[4], w2f[4];
    #pragma unroll
    for (int j = 0; j < 8; ++j) {
        int k = lq * 8 + j;
        wef[j] = (k < 16) ? (f16)W_e[(size_t)k * H + col] : (f16)0.0f;
    }
    #pragma unroll
    for (int k = 0; k < 4; ++k)
        #pragma unroll
        for (int j = 0; j < 8; ++j) {
            w1f[k][j] = (f16)W1[(size_t)(256 + k * 32 + lq * 8 + j) * H + col];
            w2f[k][j] = (f16)W2[(size_t)(k * 32 + lq * 8 + j) * H + col];
        }
    const float w1last = W1[(size_t)384 * H + col];
    const float b1v = b1[col], b2v = b2[col], bev = b_e[col];

    __shared__ alignas(16) f16 Atile[2][32][136];   // w cols only, 17.4 KB
    __shared__ alignas(16) f16 h1B[2][32][136];     // 17.4 KB
    __shared__ alignas(16) f16 Gt[2][32][136];      // Gs[src]+Gd[dst], 17.4 KB
    __shared__ int   s_src[3][32];
    __shared__ int   s_dst[3][32];
    __shared__ float s_sq[3][32];

    const int b = ((blockIdx.x & 7) << 7) | (blockIdx.x >> 3);
    const int t0 = (int)((long)b * NT_E / NB_E);
    const int t1 = (int)((long)(b + 1) * NT_E / NB_E);

    const int srow = tid >> 4, sch = tid & 15;
    const int sj = ((srow >> 2) & 3) * 8 + ((srow >> 4) << 2) + (srow & 3); // eperm

    // ---- prologue ----
    if (tid < 32) {
        int e0 = t0 * 32 + tid;
        s_src[t0 % 3][tid] = perm_src[e0];
        s_dst[t0 % 3][tid] = perm_dst[e0];
        s_sq [t0 % 3][tid] = perm_sq[e0];
        int e1 = min((t0 + 1) * 32 + tid, N_EDGES - 1);
        s_src[(t0 + 1) % 3][tid] = perm_src[e1];
        s_dst[(t0 + 1) % 3][tid] = perm_dst[e1];
        s_sq [(t0 + 1) % 3][tid] = perm_sq[e1];
    }
    __syncthreads();
    {
        const int pa = t0 & 1;
        int sv = s_src[t0 % 3][sj], dv = s_dst[t0 % 3][sj];
        union { int4 i; f16x8 h; } ua, ub, uo;
        ua.i = ((const int4*)(Gs + (size_t)sv * H))[sch];
        ub.i = ((const int4*)(Gd + (size_t)dv * H))[sch];
        #pragma unroll
        for (int j = 0; j < 8; ++j) uo.h[j] = (f16)((float)ua.h[j] + (float)ub.h[j]);
        ((int4*)&Gt[pa][srow][0])[sch] = uo.i;
        #pragma unroll
        for (int m = 0; m < 2; ++m) {
            f16x8 aa;
            if (lq < 2) {
                int j = (l16 >> 2) * 8 + m * 4 + (l16 & 3);
                aa = *(const f16x8*)(perm_ewh + (size_t)(t0 * 32 + j) * 16 + lq * 8);
            } else {
                #pragma unroll
                for (int jj = 0; jj < 8; ++jj) aa[jj] = (f16)0.0f;
            }
            f32x4 c = {bev, bev, bev, bev};
            c = __builtin_amdgcn_mfma_f32_16x16x32_f16(aa, wef, c, 0, 0, 0);
            #pragma unroll
            for (int r = 0; r < 4; ++r)
                Atile[pa][m * 16 + lq * 4 + r][col] = (f16)fmaxf(c[r], 0.0f);
        }
    }
    __syncthreads();

    int dcp[8];
    for (int t = t0; t < t1; ++t) {
        const int pa = t & 1;
        const int m0 = t % 3;
        const int m1 = (t + 1) % 3;
        const int m2 = (t + 2) % 3;

        // 1. dc(t), C-init: b1 + sq*w1last + Gsum
        int dc[8];
        f32x4 acc1[2];
        #pragma unroll
        for (int m = 0; m < 2; ++m)
            #pragma unroll
            for (int r = 0; r < 4; ++r) {
                int j = lq * 8 + m * 4 + r;
                int row = m * 16 + lq * 4 + r;
                dc[m * 4 + r] = s_dst[m0][j];
                acc1[m][r] = fmaf(s_sq[m0][j], w1last, b1v) + (float)Gt[pa][row][col];
            }

        // 2. issue Gs/Gd/ewh loads for tile t+1
        int4 ga_, gb_;
        f16x8 rew[2];
        {
            int sv = s_src[m1][sj], dv = s_dst[m1][sj];
            ga_ = ((const int4*)(Gs + (size_t)sv * H))[sch];
            gb_ = ((const int4*)(Gd + (size_t)dv * H))[sch];
            #pragma unroll
            for (int m = 0; m < 2; ++m) {
                if (lq < 2) {
                    int j = (l16 >> 2) * 8 + m * 4 + (l16 & 3);
                    int e = min((t + 1) * 32 + j, N_EDGES - 1);
                    rew[m] = *(const f16x8*)(perm_ewh + (size_t)e * 16 + lq * 8);
                }
            }
        }
        // 3. meta(t+2)
        int mrs = 0, mrd = 0; float mrq = 0.0f;
        if (tid < 32) {
            int e = min((t + 2) * 32 + tid, N_EDGES - 1);
            mrs = perm_src[e]; mrd = perm_dst[e]; mrq = perm_sq[e];
        }

        // 4+5. mm2(t-1) + atomics
        if (t > t0) {
            f32x4 acc2[2];
            #pragma unroll
            for (int m = 0; m < 2; ++m) {
                f32x4 c = {b2v, b2v, b2v, b2v};
                acc2[m] = c;
            }
            #pragma unroll
            for (int k = 0; k < 4; ++k) {
                #pragma unroll
                for (int m = 0; m < 2; ++m) {
                    f16x8 a = *(const f16x8*)&h1B[pa ^ 1][m * 16 + l16][k * 32 + lq * 8];
                    acc2[m] = __builtin_amdgcn_mfma_f32_16x16x32_f16(a, w2f[k], acc2[m], 0, 0, 0);
                }
            }
            float run = fmaxf(acc2[0][0], 0.0f);
            int cd = dcp[0];
            #pragma unroll
            for (int i = 1; i < 8; ++i) {
                float v = fmaxf(acc2[i >> 2][i & 3], 0.0f);
                int d = dcp[i];
                if (d == cd) {
                    run += v;
                } else {
                    float nb = __shfl_xor(run, 1);
                    if ((l16 & 1) == 0) {
                        union { f16 h[2]; __half2 v2; } u;
                        u.h[0] = (f16)run; u.h[1] = (f16)nb;
                        unsafeAtomicAdd((__half2*)&msum[(size_t)cd * H + col], u.v2);
                    }
                    run = v; cd = d;
                }
            }
            float nb = __shfl_xor(run, 1);
            if ((l16 & 1) == 0) {
                union { f16 h[2]; __half2 v2; } u;
                u.h[0] = (f16)run; u.h[1] = (f16)nb;
                unsafeAtomicAdd((__half2*)&msum[(size_t)cd * H + col], u.v2);
            }
        }

        // 6. mm1-w(t) -> h1B[pa]
        #pragma unroll
        for (int k = 0; k < 4; ++k) {
            #pragma unroll
            for (int m = 0; m < 2; ++m) {
                f16x8 a = *(const f16x8*)&Atile[pa][m * 16 + l16][k * 32 + lq * 8];
                acc1[m] = __builtin_amdgcn_mfma_f32_16x16x32_f16(a, w1f[k], acc1[m], 0, 0, 0);
            }
        }
        #pragma unroll
        for (int m = 0; m < 2; ++m)
            #pragma unroll
            for (int r = 0; r < 4; ++r)
                h1B[pa][m * 16 + lq * 4 + r][col] = (f16)fmaxf(acc1[m][r], 0.0f);

        // 7. we-MFMA(t+1) -> Atile[pa^1]
        #pragma unroll
        for (int m = 0; m < 2; ++m) {
            f16x8 aa;
            if (lq < 2) {
                aa = rew[m];
            } else {
                #pragma unroll
                for (int jj = 0; jj < 8; ++jj) aa[jj] = (f16)0.0f;
            }
            f32x4 c = {bev, bev, bev, bev};
            c = __builtin_amdgcn_mfma_f32_16x16x32_f16(aa, wef, c, 0, 0, 0);
            #pragma unroll
            for (int r = 0; r < 4; ++r)
                Atile[pa ^ 1][m * 16 + lq * 4 + r][col] = (f16)fmaxf(c[r], 0.0f);
        }
        // 8. Gsum(t+1) -> Gt[pa^1]
        {
            union { int4 i; f16x8 h; } ua, ub, uo;
            ua.i = ga_; ub.i = gb_;
            #pragma unroll
            for (int j = 0; j < 8; ++j) uo.h[j] = (f16)((float)ua.h[j] + (float)ub.h[j]);
            ((int4*)&Gt[pa ^ 1][srow][0])[sch] = uo.i;
        }
        // 9. meta(t+2) -> LDS
        if (tid < 32) {
            s_src[m2][tid] = mrs; s_dst[m2][tid] = mrd; s_sq[m2][tid] = mrq;
        }
        // 10. carry dc
        #pragma unroll
        for (int i = 0; i < 8; ++i) dcp[i] = dc[i];
        __syncthreads();
    }

    // ---- epilogue: mm2(t1-1) + atomics ----
    {
        const int ph = (t1 - 1) & 1;
        f32x4 acc2[2];
        #pragma unroll
        for (int m = 0; m < 2; ++m) {
            f32x4 c = {b2v, b2v, b2v, b2v};
            acc2[m] = c;
        }
        #pragma unroll
        for (int k = 0; k < 4; ++k) {
            #pragma unroll
            for (int m = 0; m < 2; ++m) {
                f16x8 a = *(const f16x8*)&h1B[ph][m * 16 + l16][k * 32 + lq * 8];
                acc2[m] = __builtin_amdgcn_mfma_f32_16x16x32_f16(a, w2f[k], acc2[m], 0, 0, 0);
            }
        }
        float run = fmaxf(acc2[0][0], 0.0f);
        int cd = dcp[0];
        #pragma unroll
        for (int i = 1; i < 8; ++i) {
            float v = fmaxf(acc2[i >> 2][i & 3], 0.0f);
            int d = dcp[i];
            if (d == cd) {
                run += v;
            } else {
                float nb = __shfl_xor(run, 1);
                if ((l16 & 1) == 0) {
                    union { f16 h[2]; __half2 v2; } u;
                    u.h[0] = (f16)run; u.h[1] = (f16)nb;
                    unsafeAtomicAdd((__half2*)&msum[(size_t)cd * H + col], u.v2);
                }
                run = v; cd = d;
            }
        }
        float nb = __shfl_xor(run, 1);
        if ((l16 & 1) == 0) {
            union { f16 h[2]; __half2 v2; } u;
            u.h[0] = (f16)run; u.h[1] = (f16)nb;
            unsafeAtomicAdd((__half2*)&msum[(size_t)cd * H + col], u.v2);
        }
    }
}

// ---------------------------------------------------------------------------
// Node update: fh = relu(relu((msum+fh)@U1+b1)@U2+b2), pipelined, 2 barriers.
// ---------------------------------------------------------------------------
__global__ __launch_bounds__(256, 3) void k_update(
    const f16* __restrict__ msum, f16* __restrict__ fh,
    const float* __restrict__ W1, const float* __restrict__ b1,
    const float* __restrict__ W2, const float* __restrict__ b2)
{
    const int tid = threadIdx.x;
    const int wave = tid >> 6;       // 0..3
    const int lane = tid & 63;
    const int l16 = lane & 15;
    const int lq = lane >> 4;
    const int colbase = wave * 32;

    f16x8 w1fr[4][2], w2fr[4][2];
    float b1v[2], b2v[2];
    #pragma unroll
    for (int nt = 0; nt < 2; ++nt) {
        const int col = colbase + nt * 16 + l16;
        #pragma unroll
        for (int k = 0; k < 4; ++k) {
            f16x8 v1, v2;
            #pragma unroll
            for (int j = 0; j < 8; ++j) {
                v1[j] = (f16)W1[(size_t)(k * 32 + lq * 8 + j) * H + col];
                v2[j] = (f16)W2[(size_t)(k * 32 + lq * 8 + j) * H + col];
            }
            w1fr[k][nt] = v1;
            w2fr[k][nt] = v2;
        }
        b1v[nt] = b1[col];
        b2v[nt] = b2[col];
    }

    __shared__ alignas(16) f16 U[32][136];
    __shared__ alignas(16) f16 h1b[32][136];
    const int row = tid >> 3, ch = tid & 7;

    int tile = blockIdx.x;
    f16x8 rm0, rm1, rf0, rf1;
    if (tile < NT_N) {
        int n = min(tile * 32 + row, N_NODES - 1);
        const f16x8* pm = (const f16x8*)(msum + (size_t)n * H) + ch * 2;
        const f16x8* pf = (const f16x8*)(fh + (size_t)n * H) + ch * 2;
        rm0 = pm[0]; rm1 = pm[1]; rf0 = pf[0]; rf1 = pf[1];
    }
    for (; tile < NT_N; tile += gridDim.x) {
        const int n0 = tile * 32;
        {
            f16 tmp[16];
            #pragma unroll
            for (int j = 0; j < 8; ++j) {
                tmp[j]     = (f16)((float)rm0[j] + (float)rf0[j]);
                tmp[8 + j] = (f16)((float)rm1[j] + (float)rf1[j]);
            }
            int4* q0 = (int4*)(&U[row][ch * 16]);
            q0[0] = ((const int4*)tmp)[0];
            q0[1] = ((const int4*)tmp)[1];
        }
        {
            int nt_ = tile + gridDim.x;
            if (nt_ < NT_N) {
                int n = min(nt_ * 32 + row, N_NODES - 1);
                const f16x8* pm = (const f16x8*)(msum + (size_t)n * H) + ch * 2;
                const f16x8* pf = (const f16x8*)(fh + (size_t)n * H) + ch * 2;
                rm0 = pm[0]; rm1 = pm[1]; rf0 = pf[0]; rf1 = pf[1];
            }
        }
        __syncthreads();   // B1

        f32x4 acc[2][2];
        #pragma unroll
        for (int m = 0; m < 2; ++m)
            #pragma unroll
            for (int nt = 0; nt < 2; ++nt) {
                f32x4 c = {b1v[nt], b1v[nt], b1v[nt], b1v[nt]};
                acc[m][nt] = c;
            }
        #pragma unroll
        for (int k = 0; k < 4; ++k) {
            #pragma unroll
            for (int m = 0; m < 2; ++m) {
                f16x8 a = *(const f16x8*)&U[m * 16 + l16][k * 32 + lq * 8];
                #pragma unroll
                for (int nt = 0; nt < 2; ++nt)
                    acc[m][nt] = __builtin_amdgcn_mfma_f32_16x16x32_f16(a, w1fr[k][nt], acc[m][nt], 0, 0, 0);
            }
        }
        #pragma unroll
        for (int m = 0; m < 2; ++m)
            #pragma unroll
            for (int nt = 0; nt < 2; ++nt)
                #pragma unroll
                for (int r = 0; r < 4; ++r)
                    h1b[m * 16 + lq * 4 + r][colbase + nt * 16 + l16] = (f16)fmaxf(acc[m][nt][r], 0.0f);
        __syncthreads();   // B2

        f32x4 acc2[2][2];
        #pragma unroll
        for (int m = 0; m < 2; ++m)
            #pragma unroll
            for (int nt = 0; nt < 2; ++nt) {
                f32x4 c = {b2v[nt], b2v[nt], b2v[nt], b2v[nt]};
                acc2[m][nt] = c;
            }
        #pragma unroll
        for (int k = 0; k < 4; ++k) {
            #pragma unroll
            for (int m = 0; m < 2; ++m) {
                f16x8 a = *(const f16x8*)&h1b[m * 16 + l16][k * 32 + lq * 8];
                #pragma unroll
                for (int nt = 0; nt < 2; ++nt)
                    acc2[m][nt] = __builtin_amdgcn_mfma_f32_16x16x32_f16(a, w2fr[k][nt], acc2[m][nt], 0, 0, 0);
            }
        }
        #pragma unroll
        for (int m = 0; m < 2; ++m)
            #pragma unroll
            for (int nt = 0; nt < 2; ++nt)
                #pragma unroll
                for (int r = 0; r < 4; ++r) {
                    int rr = m * 16 + lq * 4 + r;
                    int n = n0 + rr;
                    if (n < N_NODES)
                        fh[(size_t)n * H + colbase + nt * 16 + l16] = (f16)fmaxf(acc2[m][nt][r], 0.0f);
                }
    }
}

// ---------------------------------------------------------------------------
// Per-graph mean/max readout (graph_ids sorted; f >= 0)
// ---------------------------------------------------------------------------
__global__ void k_readout(const f16* __restrict__ fh, const int* __restrict__ gid,
                          float* __restrict__ gsum, float* __restrict__ gmax,
                          int* __restrict__ gcnt)
{
    __shared__ int s_gid[64];
    const int tid = threadIdx.x;            // 128 threads
    const int base = blockIdx.x * 64;
    if (tid < 64) s_gid[tid] = (base + tid < N_NODES) ? gid[base + tid] : -1;
    __syncthreads();
    if (tid < 64 && base + tid < N_NODES) atomicAdd(&gcnt[s_gid[tid]], 1);

    float lsum = 0.0f, lmax = 0.0f;
    int cur = s_gid[0];
    if (cur >= 0) {
        for (int i = 0; i < 64; ++i) {
            int g = s_gid[i];
            if (g < 0) break;
            if (g != cur) {
                unsafeAtomicAdd(&gsum[(size_t)cur * H + tid], lsum);
                atomicMax((int*)&gmax[(size_t)cur * H + tid], __float_as_int(lmax));
                lsum = 0.0f; lmax = 0.0f; cur = g;
            }
            float v = (float)fh[(size_t)(base + i) * H + tid];
            lsum += v;
            lmax = fmaxf(lmax, v);
        }
        unsafeAtomicAdd(&gsum[(size_t)cur * H + tid], lsum);
        atomicMax((int*)&gmax[(size_t)cur * H + tid], __float_as_int(lmax));
    }
}

__global__ void k_out(const float* __restrict__ gsum, const float* __restrict__ gmax,
                      const int* __restrict__ gcnt, const float* __restrict__ W_out,
                      const float* __restrict__ b_out, float* __restrict__ out)
{
    __shared__ float sm[128], sx[128];
    const int g = blockIdx.x, t = threadIdx.x;
    const float inv = 1.0f / fmaxf((float)gcnt[g], 1.0f);
    sm[t] = gsum[(size_t)g * H + t] * inv;
    sx[t] = gmax[(size_t)g * H + t];
    __syncthreads();
    float acc = b_out[t];
    for (int k = 0; k < H; ++k) {
        acc = fmaf(sm[k], W_out[(size_t)k * 128 + t], acc);
        acc = fmaf(sx[k], W_out[(size_t)(128 + k) * 128 + t], acc);
    }
    out[(size_t)g * 128 + t] = acc;
}

// ---------------------------------------------------------------------------
extern "C" void kernel_launch(void* const* d_in, const int* in_sizes, int n_in,
                              void* d_out, int out_size, void* d_ws, size_t ws_size,
                              hipStream_t stream)
{
    const float* node_f = (const float*)d_in[0];
    const float* node_x = (const float*)d_in[1];
    const float* edge_w = (const float*)d_in[2];
    const int*   src    = (const int*)d_in[3];
    const int*   dst    = (const int*)d_in[4];
    const int*   gid    = (const int*)d_in[5];
    const float* W_in   = (const float*)d_in[6];
    const float* b_in   = (const float*)d_in[7];
    const float* W_e    = (const float*)d_in[8];
    const float* b_e    = (const float*)d_in[9];
    const float* msg_W1 = (const float*)d_in[10];
    const float* msg_b1 = (const float*)d_in[11];
    const float* msg_W2 = (const float*)d_in[12];
    const float* msg_b2 = (const float*)d_in[13];
    const float* upd_W1 = (const float*)d_in[14];
    const float* upd_b1 = (const float*)d_in[15];
    const float* upd_W2 = (const float*)d_in[16];
    const float* upd_b2 = (const float*)d_in[17];
    const float* W_out  = (const float*)d_in[18];
    const float* b_out  = (const float*)d_in[19];
    float* out = (float*)d_out;

    char* ws = (char*)d_ws;
    size_t off = 0;
    f16*   fh       = (f16*)(ws + off);   off += (size_t)N_NODES * H * 2;      // 12.8 MB
    f16*   Gs       = (f16*)(ws + off);   off += (size_t)N_NODES * H * 2;      // 12.8 MB
    f16*   Gd       = (f16*)(ws + off);   off += (size_t)N_NODES * H * 2;      // 12.8 MB
    f16*   perm_ewh = (f16*)(ws + off);   off += (size_t)N_EDGES * 16 * 2;     // 19.2 MB
    int*   perm_src = (int*)(ws + off);   off += (size_t)N_EDGES * 4;          // 2.4 MB
    int*   perm_dst = (int*)(ws + off);   off += (size_t)N_EDGES * 4;          // 2.4 MB
    float* perm_sq  = (float*)(ws + off); off += (size_t)N_EDGES * 4;          // 2.4 MB
    int*   rowptr   = (int*)(ws + off);   off += (size_t)NP * 4;
    int*   cnt      = (int*)(ws + off);   off += (size_t)NP * 4;               // also 'fill'
    int*   bsum     = (int*)(ws + off);   off += 256 * 4;
    int*   boff     = (int*)(ws + off);   off += 256 * 4;
    f16*   msum     = (f16*)(ws + off);   off += (size_t)N_NODES * H * 2;      // 12.8 MB
    float* gsum     = (float*)(ws + off); off += (size_t)G_GRAPHS * H * 4;
    float* gmax     = (float*)(ws + off); off += (size_t)G_GRAPHS * H * 4;
    int*   gcnt     = (int*)(ws + off);   off += (size_t)G_GRAPHS * 4;
    int*   perm_eidx = (int*)msum;        // aliased: eidx only used pre-layers

    k_f0<<<(N_NODES + 7) / 8, 128, 0, stream>>>(node_f, W_in, b_in, fh);

    (void)hipMemsetAsync(cnt, 0, (size_t)NP * 4, stream);
    k_hist<<<(N_EDGES + 255) / 256, 256, 0, stream>>>(dst, cnt);
    k_scanA<<<NP / 256, 256, 0, stream>>>(cnt, rowptr, bsum);
    k_scanB<<<1, 256, 0, stream>>>(bsum, boff);
    k_scanC<<<NP / 256, 256, 0, stream>>>(rowptr, boff);
    (void)hipMemsetAsync(cnt, 0, (size_t)NP * 4, stream);
    k_scatter_idx<<<(N_EDGES + 255) / 256, 256, 0, stream>>>(dst, rowptr, cnt, perm_eidx);
    k_gather<<<(N_EDGES + 255) / 256, 256, 0, stream>>>(perm_eidx, edge_w, src, dst, node_x,
                                                        perm_src, perm_dst, perm_sq, perm_ewh);

    for (int l = 0; l < 4; ++l) {
        (void)hipMemsetAsync(msum, 0, (size_t)N_NODES * H * 2, stream);
        k_proj<<<512, 256, 0, stream>>>(fh, msg_W1 + (size_t)l * 385 * H, Gs, Gd);
        k_edge2<<<NB_E, 512, 0, stream>>>(Gs, Gd, perm_src, perm_dst, perm_sq, perm_ewh,
                                          W_e, b_e,
                                          msg_W1 + (size_t)l * 385 * H, msg_b1 + (size_t)l * H,
                                          msg_W2 + (size_t)l * H * H,  msg_b2 + (size_t)l * H,
                                          msum);
        k_update<<<512, 256, 0, stream>>>(msum, fh,
                                          upd_W1 + (size_t)l * H * H, upd_b1 + (size_t)l * H,
                                          upd_W2 + (size_t)l * H * H, upd_b2 + (size_t)l * H);
    }

    (void)hipMemsetAsync(gsum, 0, (size_t)G_GRAPHS * H * 4, stream);
    (void)hipMemsetAsync(gmax, 0, (size_t)G_GRAPHS * H * 4, stream);
    (void)hipMemsetAsync(gcnt, 0, (size_t)G_GRAPHS * 4, stream);
    k_readout<<<(N_NODES + 63) / 64, 128, 0, stream>>>(fh, gid, gsum, gmax, gcnt);
    k_out<<<G_GRAPHS, 128, 0, stream>>>(gsum, gmax, gcnt, W_out, b_out, out);
}